// Round 3
// baseline (282864.355 us; speedup 1.0000x reference)
//
#include <hip/hip_runtime.h>
#include <hip/hip_bf16.h>
#include <math.h>

#define NPTS 2048
#define NCLOUD 32
#define NTOT (NPTS*NCLOUD)
#define CIN 64
#define COUT 128
#define KNN 16
#define KCAND 20          // candidates kept per column segment
#define NSEG 4            // column segments per cloud
#define CSEG (NPTS/NSEG)  // 512 columns per segment
#define NCAND (KCAND*NSEG) // 80 candidates per point
#define TC 128            // K1 LDS column tile

// ---------------- K1: per-row fp32 ranking over a 512-column segment, top-20 ----------------
// grid = NCLOUD * 8 rowblocks * NSEG = 1024 blocks -> 4 blocks/CU, 4 waves/SIMD.
__global__ __launch_bounds__(256,4) void k1_knn(const float* __restrict__ x, int* __restrict__ cand)
{
    __shared__ float xt[TC*68];   // [col][68] padded
    __shared__ float sqq[TC];
    const int b      = blockIdx.x >> 5;          // 32 blocks per cloud
    const int rowblk = (blockIdx.x >> 2) & 7;
    const int colseg = blockIdx.x & 3;
    const int t      = threadIdx.x;
    const int p      = rowblk*256 + t;           // my row within cloud
    const float* xc  = x + (size_t)b * NPTS * CIN;

    float xp[CIN];
    #pragma unroll
    for (int i = 0; i < CIN/4; ++i) {
        float4 v = *reinterpret_cast<const float4*>(xc + (size_t)p*CIN + 4*i);
        xp[4*i+0]=v.x; xp[4*i+1]=v.y; xp[4*i+2]=v.z; xp[4*i+3]=v.w;
    }

    // sorted descending: ld[0] = worst kept
    float ld[KCAND]; int li[KCAND];
    #pragma unroll
    for (int j = 0; j < KCAND; ++j) { ld[j] = INFINITY; li[j] = 0; }

    for (int tile = 0; tile < CSEG/TC; ++tile) {   // 4 tiles of 128 cols
        const int cbase = colseg*CSEG + tile*TC;
        __syncthreads();
        if (t < TC) {
            const float* src = xc + (size_t)(cbase + t) * CIN;
            float s = 0.f;
            #pragma unroll
            for (int i = 0; i < CIN/4; ++i) {
                float4 v = *reinterpret_cast<const float4*>(src + 4*i);
                *reinterpret_cast<float4*>(&xt[t*68 + 4*i]) = v;
                s += v.x*v.x + v.y*v.y + v.z*v.z + v.w*v.w;
            }
            sqq[t] = s;
        }
        __syncthreads();
        for (int q = 0; q < TC; ++q) {
            float a0=0.f,a1=0.f,a2=0.f,a3=0.f;
            #pragma unroll
            for (int i = 0; i < CIN/4; ++i) {
                float4 v = *reinterpret_cast<const float4*>(&xt[q*68 + 4*i]); // wave-uniform broadcast
                a0 = fmaf(v.x, xp[4*i+0], a0);
                a1 = fmaf(v.y, xp[4*i+1], a1);
                a2 = fmaf(v.z, xp[4*i+2], a2);
                a3 = fmaf(v.w, xp[4*i+3], a3);
            }
            float s = sqq[q] - 2.f*((a0+a1)+(a2+a3));   // rank-equivalent to d^2
            const int gq = cbase + q;
            if (s < ld[0] && gq != p) {
                ld[0] = s; li[0] = gq;
                #pragma unroll
                for (int j = 0; j < KCAND-1; ++j) {
                    if (ld[j] < ld[j+1]) {
                        float td = ld[j]; ld[j] = ld[j+1]; ld[j+1] = td;
                        int   ti = li[j]; li[j] = li[j+1]; li[j+1] = ti;
                    }
                }
            }
        }
    }
    int* dst = cand + (size_t)(b*NPTS + p) * NCAND + colseg*KCAND;
    #pragma unroll
    for (int j = 0; j < KCAND; ++j) dst[j] = li[j];
}

// np.sum pairwise-8 replication for 64 squares (fp32, no FMA) — keep BIT-IDENTICAL to round 2.
__device__ __forceinline__ float np_sq64(const float* __restrict__ v)
{
    float r[8];
    #pragma unroll
    for (int j = 0; j < 8; ++j) r[j] = __fmul_rn(v[j], v[j]);
    #pragma unroll
    for (int i = 1; i < 8; ++i)
        #pragma unroll
        for (int j = 0; j < 8; ++j) r[j] = __fadd_rn(r[j], __fmul_rn(v[8*i+j], v[8*i+j]));
    return __fadd_rn(__fadd_rn(__fadd_rn(r[0],r[1]), __fadd_rn(r[2],r[3])),
                     __fadd_rn(__fadd_rn(r[4],r[5]), __fadd_rn(r[6],r[7])));
}

// ---------------- K2: thread-per-point fp32-faithful rerank of 80 candidates -> top-16 set ----------------
__global__ void k2_refine(const float* __restrict__ x, const int* __restrict__ cand, int* __restrict__ nbr)
{
    const int pg = blockIdx.x * blockDim.x + threadIdx.x;   // global point id
    const int b  = pg >> 11;
    const int p  = pg & (NPTS-1);
    const float* xc = x + (size_t)b * NPTS * CIN;
    const float* xp = xc + (size_t)p * CIN;

    float xpl[CIN];
    #pragma unroll
    for (int i = 0; i < CIN/4; ++i) {
        float4 v = *reinterpret_cast<const float4*>(xp + 4*i);
        xpl[4*i+0]=v.x; xpl[4*i+1]=v.y; xpl[4*i+2]=v.z; xpl[4*i+3]=v.w;
    }
    const float sqp = np_sq64(xpl);

    // sorted by "worseness" descending: slot 0 = worst kept. worse = (d larger) or (d equal, idx larger)
    float ld[KNN]; int li[KNN];
    #pragma unroll
    for (int j = 0; j < KNN; ++j) { ld[j] = INFINITY; li[j] = 0x7fffffff; }

    const int* cp = cand + (size_t)pg * NCAND;
    #pragma unroll 2
    for (int j = 0; j < NCAND; ++j) {
        const int q = cp[j];
        const float* xq = xc + (size_t)q * CIN;
        // stream xq 8 floats at a time; replicate np_sq64 reduction + sequential no-FMA dot
        float r[8];
        float dot = 0.f;
        {
            float4 v0 = *reinterpret_cast<const float4*>(xq + 0);
            float4 v1 = *reinterpret_cast<const float4*>(xq + 4);
            float g[8] = {v0.x,v0.y,v0.z,v0.w,v1.x,v1.y,v1.z,v1.w};
            #pragma unroll
            for (int u = 0; u < 8; ++u) {
                r[u] = __fmul_rn(g[u], g[u]);
                dot  = __fadd_rn(dot, __fmul_rn(xpl[u], g[u]));
            }
        }
        #pragma unroll
        for (int i = 1; i < 8; ++i) {
            float4 v0 = *reinterpret_cast<const float4*>(xq + 8*i);
            float4 v1 = *reinterpret_cast<const float4*>(xq + 8*i + 4);
            float g[8] = {v0.x,v0.y,v0.z,v0.w,v1.x,v1.y,v1.z,v1.w};
            #pragma unroll
            for (int u = 0; u < 8; ++u) {
                r[u] = __fadd_rn(r[u], __fmul_rn(g[u], g[u]));
                dot  = __fadd_rn(dot, __fmul_rn(xpl[8*i+u], g[u]));
            }
        }
        const float sqq = __fadd_rn(__fadd_rn(__fadd_rn(r[0],r[1]), __fadd_rn(r[2],r[3])),
                                    __fadd_rn(__fadd_rn(r[4],r[5]), __fadd_rn(r[6],r[7])));
        const float d = __fsub_rn(__fadd_rn(sqp, sqq), __fmul_rn(2.f, dot));

        const bool better = (d < ld[0]) || (d == ld[0] && q < li[0]);
        if (better) {
            ld[0] = d; li[0] = q;
            #pragma unroll
            for (int k = 0; k < KNN-1; ++k) {
                const bool sw = (ld[k] < ld[k+1]) || (ld[k] == ld[k+1] && li[k] < li[k+1]);
                if (sw) {
                    float td = ld[k]; ld[k] = ld[k+1]; ld[k+1] = td;
                    int   ti = li[k]; li[k] = li[k+1]; li[k+1] = ti;
                }
            }
        }
    }
    int* dst = nbr + (size_t)pg * KNN;
    #pragma unroll
    for (int j = 0; j < KNN; ++j) dst[j] = b * NPTS + li[j];   // set only; order irrelevant (max-pool)
}

// ---------------- K3: scatter-max pooled[n] = max over centers c with n in knn(c) of x[c] ----------------
__global__ void k3_scatter(const float* __restrict__ x, const int* __restrict__ nbr, float* __restrict__ pooled)
{
    const int gtid = blockIdx.x * blockDim.x + threadIdx.x;
    const int c    = gtid >> 6;                 // center point, one wave each
    const int lane = threadIdx.x & 63;          // channel
    const float v  = x[(size_t)c * CIN + lane];
    const int   vi = __float_as_int(v);
    const unsigned vu = __float_as_uint(v);
    #pragma unroll
    for (int k = 0; k < KNN; ++k) {
        const int n = nbr[(size_t)c * KNN + k];
        float* addr = &pooled[(size_t)n * CIN + lane];
        if (v >= 0.f) atomicMax((int*)addr, vi);        // pos floats: int order == float order
        else          atomicMin((unsigned*)addr, vu);   // neg floats: uint order reversed
    }
}

// ---------------- K4: y = pooled @ W^T + b (64x128 tile per block) ----------------
__global__ __launch_bounds__(256,2) void k4_linear(const float* __restrict__ pooled, const float* __restrict__ W,
                                                   const float* __restrict__ bias, float* __restrict__ y)
{
    __shared__ float wl[COUT*68];   // [c][k] padded
    __shared__ float pl[64*68];     // [r][k] padded
    const int t  = threadIdx.x;
    const int r0 = blockIdx.x * 64;
    for (int i = 0; i < (COUT*CIN)/256; ++i) {
        int linear = t + 256*i;
        int c = linear >> 6, k = linear & 63;
        wl[c*68 + k] = W[linear];
    }
    for (int i = 0; i < (64*CIN)/256; ++i) {
        int linear = t + 256*i;
        int r = linear >> 6, k = linear & 63;
        float v = pooled[(size_t)(r0 + r)*CIN + k];
        if (v != v) v = 0.f;                            // NaN marker = empty row -> 0
        pl[r*68 + k] = v;
    }
    __syncthreads();
    const int tx = t & 15;
    const int ty = t >> 4;
    float acc[4][8];
    #pragma unroll
    for (int j = 0; j < 8; ++j) {
        float bj = bias[tx + 16*j];
        #pragma unroll
        for (int i = 0; i < 4; ++i) acc[i][j] = bj;
    }
    for (int k = 0; k < CIN; k += 4) {
        float4 a[4], bb[8];
        #pragma unroll
        for (int i = 0; i < 4; ++i) a[i]  = *reinterpret_cast<const float4*>(&pl[(ty*4+i)*68 + k]);
        #pragma unroll
        for (int j = 0; j < 8; ++j) bb[j] = *reinterpret_cast<const float4*>(&wl[(tx+16*j)*68 + k]);
        #pragma unroll
        for (int i = 0; i < 4; ++i)
            #pragma unroll
            for (int j = 0; j < 8; ++j) {
                acc[i][j] = fmaf(a[i].x, bb[j].x, acc[i][j]);
                acc[i][j] = fmaf(a[i].y, bb[j].y, acc[i][j]);
                acc[i][j] = fmaf(a[i].z, bb[j].z, acc[i][j]);
                acc[i][j] = fmaf(a[i].w, bb[j].w, acc[i][j]);
            }
    }
    #pragma unroll
    for (int i = 0; i < 4; ++i) {
        float* dst = y + (size_t)(r0 + ty*4 + i) * COUT;
        #pragma unroll
        for (int j = 0; j < 8; ++j) dst[tx + 16*j] = acc[i][j];
    }
}

// ---------------- K5: per-channel sum / sumsq (fp64 accumulation) ----------------
__global__ void k5_stats(const float* __restrict__ y, double* __restrict__ sums)
{
    __shared__ double red[512];
    const int t    = threadIdx.x;
    const int ch   = t & 127;
    const int half = t >> 7;
    const size_t base = (size_t)blockIdx.x * 256;
    double s = 0.0, ss = 0.0;
    for (int r = 0; r < 128; ++r) {
        double v = (double)y[(base + (size_t)half*128 + r) * COUT + ch];
        s += v; ss += v*v;
    }
    red[t] = s; red[256 + t] = ss;
    __syncthreads();
    if (half == 0) {
        atomicAdd(&sums[ch],        s  + red[128 + ch]);
        atomicAdd(&sums[COUT + ch], ss + red[256 + 128 + ch]);
    }
}

// ---------------- K6: BN scale/shift ----------------
__global__ void k6_bnparam(const double* __restrict__ sums, const float* __restrict__ gamma,
                           const float* __restrict__ beta, float* __restrict__ scsh)
{
    const int t = threadIdx.x;
    const double mean = sums[t] * (1.0/NTOT);
    const double var  = sums[COUT + t] * (1.0/NTOT) - mean*mean;
    const float inv   = (float)rsqrt(var + 1e-5);
    const float sc    = inv * gamma[t];
    scsh[t]        = sc;
    scsh[COUT + t] = beta[t] - (float)mean * sc;
}

// ---------------- K7: out = relu(y*scale + shift) ----------------
__global__ void k7_bnrelu(const float* __restrict__ y, const float* __restrict__ scsh, float* __restrict__ out)
{
    const int g    = blockIdx.x * blockDim.x + threadIdx.x;
    const int base = g * 4;
    float4 v = *reinterpret_cast<const float4*>(y + base);
    const int ch = base & (COUT-1);
    float4 o;
    o.x = fmaxf(0.f, fmaf(v.x, scsh[ch+0], scsh[COUT+ch+0]));
    o.y = fmaxf(0.f, fmaf(v.y, scsh[ch+1], scsh[COUT+ch+1]));
    o.z = fmaxf(0.f, fmaf(v.z, scsh[ch+2], scsh[COUT+ch+2]));
    o.w = fmaxf(0.f, fmaf(v.w, scsh[ch+3], scsh[COUT+ch+3]));
    *reinterpret_cast<float4*>(out + base) = o;
}

extern "C" void kernel_launch(void* const* d_in, const int* in_sizes, int n_in,
                              void* d_out, int out_size, void* d_ws, size_t ws_size,
                              hipStream_t stream)
{
    const float* x     = (const float*)d_in[0];
    const float* W     = (const float*)d_in[2];
    const float* bias  = (const float*)d_in[3];
    const float* gamma = (const float*)d_in[4];
    const float* beta  = (const float*)d_in[5];
    float* out = (float*)d_out;

    // Workspace layout (overlapping: cand is dead after k2, pooled/y reuse it):
    //  [0 .. 16.8M)      pooled (aliases cand)          -- memset AFTER k2 in stream order
    //  [0 .. 21M)        cand   (k1 out, k2 in)
    //  [16.8M .. 50.4M)  y      (aliases cand tail)
    //  [50.4M .. 54.6M)  nbr
    //  [54.6M .. )       sums (f64) + scsh
    char* ws = (char*)d_ws;
    int*    cand   = (int*)ws;                                   // NTOT*80 ints
    float*  pooled = (float*)ws;                                 // NTOT*64 f32 (reuse)
    float*  y      = (float*)(ws + (size_t)NTOT*CIN*4);          // NTOT*128 f32
    int*    nbr    = (int*)(ws + (size_t)NTOT*(CIN+COUT)*4);     // NTOT*16 ints
    double* sums   = (double*)(ws + (size_t)NTOT*(CIN+COUT+KNN)*4); // 2*COUT f64
    float*  scsh   = (float*)((char*)sums + 2*COUT*sizeof(double));

    k1_knn   <<<NCLOUD*8*NSEG, 256, 0, stream>>>(x, cand);
    k2_refine<<<NTOT/256,      256, 0, stream>>>(x, cand, nbr);

    hipMemsetAsync(pooled, 0xFF, (size_t)NTOT*CIN*4, stream);  // NaN marker (cand dead now)
    hipMemsetAsync(sums, 0, 2*COUT*sizeof(double), stream);

    k3_scatter<<<NTOT/4,  256, 0, stream>>>(x, nbr, pooled);
    k4_linear <<<NTOT/64, 256, 0, stream>>>(pooled, W, bias, y);
    k5_stats  <<<NTOT/256,256, 0, stream>>>(y, sums);
    k6_bnparam<<<1,      COUT, 0, stream>>>(sums, gamma, beta, scsh);
    k7_bnrelu <<<(NTOT*COUT/4)/256, 256, 0, stream>>>(y, scsh, out);
}

// Round 4
// 1824.385 us; speedup vs baseline: 155.0464x; 155.0464x over previous
//
#include <hip/hip_runtime.h>
#include <hip/hip_bf16.h>
#include <math.h>

#define NPTS 2048
#define NCLOUD 32
#define NTOT (NPTS*NCLOUD)
#define CIN 64
#define COUT 128
#define KNN 16
#define KCAND 20          // candidates kept per column segment
#define NSEG 4            // column segments per cloud
#define CSEG (NPTS/NSEG)  // 512 columns per segment
#define NCAND (KCAND*NSEG) // 80 candidates per point
#define TC 128            // K1 LDS column tile

// ---------------- K1: per-row fp32 ranking over a 512-column segment, top-20 ----------------
// grid = NCLOUD * 8 rowblocks * NSEG = 1024 blocks -> 4 blocks/CU (LDS-limited).
// __launch_bounds__(256,1): do NOT cap VGPRs — forcing 4 waves/EU made the
// allocator pick 64 VGPRs and spill xp[64] to scratch (966 GB of scratch
// traffic, 190x regression in round 3). At VGPR<=128 all 4 blocks co-reside.
__global__ __launch_bounds__(256,1) void k1_knn(const float* __restrict__ x, int* __restrict__ cand)
{
    __shared__ float xt[TC*68];   // [col][68] padded
    __shared__ float sqq[TC];
    const int b      = blockIdx.x >> 5;          // 32 blocks per cloud
    const int rowblk = (blockIdx.x >> 2) & 7;
    const int colseg = blockIdx.x & 3;
    const int t      = threadIdx.x;
    const int p      = rowblk*256 + t;           // my row within cloud
    const float* xc  = x + (size_t)b * NPTS * CIN;

    float xp[CIN];
    #pragma unroll
    for (int i = 0; i < CIN/4; ++i) {
        float4 v = *reinterpret_cast<const float4*>(xc + (size_t)p*CIN + 4*i);
        xp[4*i+0]=v.x; xp[4*i+1]=v.y; xp[4*i+2]=v.z; xp[4*i+3]=v.w;
    }

    // sorted descending: ld[0] = worst kept
    float ld[KCAND]; int li[KCAND];
    #pragma unroll
    for (int j = 0; j < KCAND; ++j) { ld[j] = INFINITY; li[j] = 0; }

    for (int tile = 0; tile < CSEG/TC; ++tile) {   // 4 tiles of 128 cols
        const int cbase = colseg*CSEG + tile*TC;
        __syncthreads();
        if (t < TC) {
            const float* src = xc + (size_t)(cbase + t) * CIN;
            float s = 0.f;
            #pragma unroll
            for (int i = 0; i < CIN/4; ++i) {
                float4 v = *reinterpret_cast<const float4*>(src + 4*i);
                *reinterpret_cast<float4*>(&xt[t*68 + 4*i]) = v;
                s += v.x*v.x + v.y*v.y + v.z*v.z + v.w*v.w;
            }
            sqq[t] = s;
        }
        __syncthreads();
        #pragma unroll 2
        for (int q = 0; q < TC; ++q) {
            float a0=0.f,a1=0.f,a2=0.f,a3=0.f;
            #pragma unroll
            for (int i = 0; i < CIN/4; ++i) {
                float4 v = *reinterpret_cast<const float4*>(&xt[q*68 + 4*i]); // wave-uniform broadcast
                a0 = fmaf(v.x, xp[4*i+0], a0);
                a1 = fmaf(v.y, xp[4*i+1], a1);
                a2 = fmaf(v.z, xp[4*i+2], a2);
                a3 = fmaf(v.w, xp[4*i+3], a3);
            }
            float s = sqq[q] - 2.f*((a0+a1)+(a2+a3));   // rank-equivalent to d^2
            const int gq = cbase + q;
            if (s < ld[0] && gq != p) {
                ld[0] = s; li[0] = gq;
                #pragma unroll
                for (int j = 0; j < KCAND-1; ++j) {
                    if (ld[j] < ld[j+1]) {
                        float td = ld[j]; ld[j] = ld[j+1]; ld[j+1] = td;
                        int   ti = li[j]; li[j] = li[j+1]; li[j+1] = ti;
                    }
                }
            }
        }
    }
    int* dst = cand + (size_t)(b*NPTS + p) * NCAND + colseg*KCAND;
    #pragma unroll
    for (int j = 0; j < KCAND; ++j) dst[j] = li[j];
}

// np.sum pairwise-8 replication for 64 squares (fp32, no FMA) — keep BIT-IDENTICAL.
__device__ __forceinline__ float np_sq64(const float* __restrict__ v)
{
    float r[8];
    #pragma unroll
    for (int j = 0; j < 8; ++j) r[j] = __fmul_rn(v[j], v[j]);
    #pragma unroll
    for (int i = 1; i < 8; ++i)
        #pragma unroll
        for (int j = 0; j < 8; ++j) r[j] = __fadd_rn(r[j], __fmul_rn(v[8*i+j], v[8*i+j]));
    return __fadd_rn(__fadd_rn(__fadd_rn(r[0],r[1]), __fadd_rn(r[2],r[3])),
                     __fadd_rn(__fadd_rn(r[4],r[5]), __fadd_rn(r[6],r[7])));
}

// ---------------- K2: thread-per-point fp32-faithful rerank of 80 candidates -> top-16 set ----------------
__global__ void k2_refine(const float* __restrict__ x, const int* __restrict__ cand, int* __restrict__ nbr)
{
    const int pg = blockIdx.x * blockDim.x + threadIdx.x;   // global point id
    const int b  = pg >> 11;
    const int p  = pg & (NPTS-1);
    const float* xc = x + (size_t)b * NPTS * CIN;
    const float* xp = xc + (size_t)p * CIN;

    float xpl[CIN];
    #pragma unroll
    for (int i = 0; i < CIN/4; ++i) {
        float4 v = *reinterpret_cast<const float4*>(xp + 4*i);
        xpl[4*i+0]=v.x; xpl[4*i+1]=v.y; xpl[4*i+2]=v.z; xpl[4*i+3]=v.w;
    }
    const float sqp = np_sq64(xpl);

    // sorted by "worseness" descending: slot 0 = worst kept
    float ld[KNN]; int li[KNN];
    #pragma unroll
    for (int j = 0; j < KNN; ++j) { ld[j] = INFINITY; li[j] = 0x7fffffff; }

    const int* cp = cand + (size_t)pg * NCAND;
    #pragma unroll 2
    for (int j = 0; j < NCAND; ++j) {
        const int q = cp[j];
        const float* xq = xc + (size_t)q * CIN;
        float r[8];
        float dot = 0.f;
        {
            float4 v0 = *reinterpret_cast<const float4*>(xq + 0);
            float4 v1 = *reinterpret_cast<const float4*>(xq + 4);
            float g[8] = {v0.x,v0.y,v0.z,v0.w,v1.x,v1.y,v1.z,v1.w};
            #pragma unroll
            for (int u = 0; u < 8; ++u) {
                r[u] = __fmul_rn(g[u], g[u]);
                dot  = __fadd_rn(dot, __fmul_rn(xpl[u], g[u]));
            }
        }
        #pragma unroll
        for (int i = 1; i < 8; ++i) {
            float4 v0 = *reinterpret_cast<const float4*>(xq + 8*i);
            float4 v1 = *reinterpret_cast<const float4*>(xq + 8*i + 4);
            float g[8] = {v0.x,v0.y,v0.z,v0.w,v1.x,v1.y,v1.z,v1.w};
            #pragma unroll
            for (int u = 0; u < 8; ++u) {
                r[u] = __fadd_rn(r[u], __fmul_rn(g[u], g[u]));
                dot  = __fadd_rn(dot, __fmul_rn(xpl[8*i+u], g[u]));
            }
        }
        const float sqq = __fadd_rn(__fadd_rn(__fadd_rn(r[0],r[1]), __fadd_rn(r[2],r[3])),
                                    __fadd_rn(__fadd_rn(r[4],r[5]), __fadd_rn(r[6],r[7])));
        const float d = __fsub_rn(__fadd_rn(sqp, sqq), __fmul_rn(2.f, dot));

        const bool better = (d < ld[0]) || (d == ld[0] && q < li[0]);
        if (better) {
            ld[0] = d; li[0] = q;
            #pragma unroll
            for (int k = 0; k < KNN-1; ++k) {
                const bool sw = (ld[k] < ld[k+1]) || (ld[k] == ld[k+1] && li[k] < li[k+1]);
                if (sw) {
                    float td = ld[k]; ld[k] = ld[k+1]; ld[k+1] = td;
                    int   ti = li[k]; li[k] = li[k+1]; li[k+1] = ti;
                }
            }
        }
    }
    int* dst = nbr + (size_t)pg * KNN;
    #pragma unroll
    for (int j = 0; j < KNN; ++j) dst[j] = b * NPTS + li[j];   // set only; order irrelevant (max-pool)
}

// ---------------- K3: scatter-max pooled[n] = max over centers c with n in knn(c) of x[c] ----------------
__global__ void k3_scatter(const float* __restrict__ x, const int* __restrict__ nbr, float* __restrict__ pooled)
{
    const int gtid = blockIdx.x * blockDim.x + threadIdx.x;
    const int c    = gtid >> 6;                 // center point, one wave each
    const int lane = threadIdx.x & 63;          // channel
    const float v  = x[(size_t)c * CIN + lane];
    const int   vi = __float_as_int(v);
    const unsigned vu = __float_as_uint(v);
    #pragma unroll
    for (int k = 0; k < KNN; ++k) {
        const int n = nbr[(size_t)c * KNN + k];
        float* addr = &pooled[(size_t)n * CIN + lane];
        if (v >= 0.f) atomicMax((int*)addr, vi);        // pos floats: int order == float order
        else          atomicMin((unsigned*)addr, vu);   // neg floats: uint order reversed
    }
}

// ---------------- K4: y = pooled @ W^T + b (64x128 tile per block) ----------------
__global__ __launch_bounds__(256,2) void k4_linear(const float* __restrict__ pooled, const float* __restrict__ W,
                                                   const float* __restrict__ bias, float* __restrict__ y)
{
    __shared__ float wl[COUT*68];   // [c][k] padded
    __shared__ float pl[64*68];     // [r][k] padded
    const int t  = threadIdx.x;
    const int r0 = blockIdx.x * 64;
    for (int i = 0; i < (COUT*CIN)/256; ++i) {
        int linear = t + 256*i;
        int c = linear >> 6, k = linear & 63;
        wl[c*68 + k] = W[linear];
    }
    for (int i = 0; i < (64*CIN)/256; ++i) {
        int linear = t + 256*i;
        int r = linear >> 6, k = linear & 63;
        float v = pooled[(size_t)(r0 + r)*CIN + k];
        if (v != v) v = 0.f;                            // NaN marker = empty row -> 0
        pl[r*68 + k] = v;
    }
    __syncthreads();
    const int tx = t & 15;
    const int ty = t >> 4;
    float acc[4][8];
    #pragma unroll
    for (int j = 0; j < 8; ++j) {
        float bj = bias[tx + 16*j];
        #pragma unroll
        for (int i = 0; i < 4; ++i) acc[i][j] = bj;
    }
    for (int k = 0; k < CIN; k += 4) {
        float4 a[4], bb[8];
        #pragma unroll
        for (int i = 0; i < 4; ++i) a[i]  = *reinterpret_cast<const float4*>(&pl[(ty*4+i)*68 + k]);
        #pragma unroll
        for (int j = 0; j < 8; ++j) bb[j] = *reinterpret_cast<const float4*>(&wl[(tx+16*j)*68 + k]);
        #pragma unroll
        for (int i = 0; i < 4; ++i)
            #pragma unroll
            for (int j = 0; j < 8; ++j) {
                acc[i][j] = fmaf(a[i].x, bb[j].x, acc[i][j]);
                acc[i][j] = fmaf(a[i].y, bb[j].y, acc[i][j]);
                acc[i][j] = fmaf(a[i].z, bb[j].z, acc[i][j]);
                acc[i][j] = fmaf(a[i].w, bb[j].w, acc[i][j]);
            }
    }
    #pragma unroll
    for (int i = 0; i < 4; ++i) {
        float* dst = y + (size_t)(r0 + ty*4 + i) * COUT;
        #pragma unroll
        for (int j = 0; j < 8; ++j) dst[tx + 16*j] = acc[i][j];
    }
}

// ---------------- K5: per-channel sum / sumsq (fp64 accumulation) ----------------
__global__ void k5_stats(const float* __restrict__ y, double* __restrict__ sums)
{
    __shared__ double red[512];
    const int t    = threadIdx.x;
    const int ch   = t & 127;
    const int half = t >> 7;
    const size_t base = (size_t)blockIdx.x * 256;
    double s = 0.0, ss = 0.0;
    for (int r = 0; r < 128; ++r) {
        double v = (double)y[(base + (size_t)half*128 + r) * COUT + ch];
        s += v; ss += v*v;
    }
    red[t] = s; red[256 + t] = ss;
    __syncthreads();
    if (half == 0) {
        atomicAdd(&sums[ch],        s  + red[128 + ch]);
        atomicAdd(&sums[COUT + ch], ss + red[256 + 128 + ch]);
    }
}

// ---------------- K6: BN scale/shift ----------------
__global__ void k6_bnparam(const double* __restrict__ sums, const float* __restrict__ gamma,
                           const float* __restrict__ beta, float* __restrict__ scsh)
{
    const int t = threadIdx.x;
    const double mean = sums[t] * (1.0/NTOT);
    const double var  = sums[COUT + t] * (1.0/NTOT) - mean*mean;
    const float inv   = (float)rsqrt(var + 1e-5);
    const float sc    = inv * gamma[t];
    scsh[t]        = sc;
    scsh[COUT + t] = beta[t] - (float)mean * sc;
}

// ---------------- K7: out = relu(y*scale + shift) ----------------
__global__ void k7_bnrelu(const float* __restrict__ y, const float* __restrict__ scsh, float* __restrict__ out)
{
    const int g    = blockIdx.x * blockDim.x + threadIdx.x;
    const int base = g * 4;
    float4 v = *reinterpret_cast<const float4*>(y + base);
    const int ch = base & (COUT-1);
    float4 o;
    o.x = fmaxf(0.f, fmaf(v.x, scsh[ch+0], scsh[COUT+ch+0]));
    o.y = fmaxf(0.f, fmaf(v.y, scsh[ch+1], scsh[COUT+ch+1]));
    o.z = fmaxf(0.f, fmaf(v.z, scsh[ch+2], scsh[COUT+ch+2]));
    o.w = fmaxf(0.f, fmaf(v.w, scsh[ch+3], scsh[COUT+ch+3]));
    *reinterpret_cast<float4*>(out + base) = o;
}

extern "C" void kernel_launch(void* const* d_in, const int* in_sizes, int n_in,
                              void* d_out, int out_size, void* d_ws, size_t ws_size,
                              hipStream_t stream)
{
    const float* x     = (const float*)d_in[0];
    const float* W     = (const float*)d_in[2];
    const float* bias  = (const float*)d_in[3];
    const float* gamma = (const float*)d_in[4];
    const float* beta  = (const float*)d_in[5];
    float* out = (float*)d_out;

    // Workspace layout (overlapping: cand is dead after k2, pooled/y reuse it)
    char* ws = (char*)d_ws;
    int*    cand   = (int*)ws;                                   // NTOT*80 ints
    float*  pooled = (float*)ws;                                 // NTOT*64 f32 (reuse)
    float*  y      = (float*)(ws + (size_t)NTOT*CIN*4);          // NTOT*128 f32
    int*    nbr    = (int*)(ws + (size_t)NTOT*(CIN+COUT)*4);     // NTOT*16 ints
    double* sums   = (double*)(ws + (size_t)NTOT*(CIN+COUT+KNN)*4); // 2*COUT f64
    float*  scsh   = (float*)((char*)sums + 2*COUT*sizeof(double));

    k1_knn   <<<NCLOUD*8*NSEG, 256, 0, stream>>>(x, cand);
    k2_refine<<<NTOT/256,      256, 0, stream>>>(x, cand, nbr);

    hipMemsetAsync(pooled, 0xFF, (size_t)NTOT*CIN*4, stream);  // NaN marker (cand dead now)
    hipMemsetAsync(sums, 0, 2*COUT*sizeof(double), stream);

    k3_scatter<<<NTOT/4,  256, 0, stream>>>(x, nbr, pooled);
    k4_linear <<<NTOT/64, 256, 0, stream>>>(pooled, W, bias, y);
    k5_stats  <<<NTOT/256,256, 0, stream>>>(y, sums);
    k6_bnparam<<<1,      COUT, 0, stream>>>(sums, gamma, beta, scsh);
    k7_bnrelu <<<(NTOT*COUT/4)/256, 256, 0, stream>>>(y, scsh, out);
}

// Round 5
// 1121.699 us; speedup vs baseline: 252.1750x; 1.6264x over previous
//
#include <hip/hip_runtime.h>
#include <hip/hip_bf16.h>
#include <math.h>

#define NPTS 2048
#define NCLOUD 32
#define NTOT (NPTS*NCLOUD)
#define CIN 64
#define COUT 128
#define KNN 16
#define KSUB 16            // per-lane-subset kept candidates (16 = provably exact superset)
#define NCAND 64           // 4 subsets * 16

typedef __attribute__((ext_vector_type(8))) short short8v;   // 8 bf16 (4 VGPR)
typedef __attribute__((ext_vector_type(4))) float float4v;   // 4 fp32

__device__ __forceinline__ unsigned short f2bf(float f) {    // RNE float->bf16
    unsigned u = __float_as_uint(f);
    return (unsigned short)((u + 0x7fffu + ((u >> 16) & 1u)) >> 16);
}
__device__ __forceinline__ float bf2f(unsigned short h) {
    return __uint_as_float(((unsigned)h) << 16);
}

// ---------------- K0: bf16 hi/lo planes + |q|^2 (fp32, ranking-only) ----------------
__global__ void k0_prep(const float* __restrict__ x, unsigned short* __restrict__ xhi,
                        unsigned short* __restrict__ xlo, float* __restrict__ sq)
{
    const int p = blockIdx.x * 256 + threadIdx.x;
    const float* src = x + (size_t)p * CIN;
    float s = 0.f;
    #pragma unroll
    for (int i = 0; i < 8; ++i) {                  // 8 floats per step
        float4 v0 = *reinterpret_cast<const float4*>(src + 8*i);
        float4 v1 = *reinterpret_cast<const float4*>(src + 8*i + 4);
        float e[8] = {v0.x,v0.y,v0.z,v0.w,v1.x,v1.y,v1.z,v1.w};
        short8v h, l;
        #pragma unroll
        for (int u = 0; u < 8; ++u) {
            unsigned short hb = f2bf(e[u]);
            h[u] = (short)hb;
            l[u] = (short)f2bf(e[u] - bf2f(hb));   // residual, exact subtract
            s = fmaf(e[u], e[u], s);
        }
        *reinterpret_cast<short8v*>(xhi + (size_t)p*CIN + 8*i) = h;
        *reinterpret_cast<short8v*>(xlo + (size_t)p*CIN + 8*i) = l;
    }
    sq[p] = s;
}

// ---------------- K1: MFMA swapped-operand KNN candidate generation ----------------
// Block = 256 threads = 4 waves; wave owns 16 rows (j = lane&15); lane quad (lane>>4)
// covers column subset {quad*4+r + 16*it}. Per-lane register top-16 over its 512-col
// subset -> union of 4 subsets is a provable superset of the true top-16.
// No LDS, no barriers. bf16 hi/lo split: dot = Ahi*Bhi + Ahi*Blo + Alo*Bhi (err ~1e-3,
// ranking only; exact np-faithful rerank in k2).
__global__ __launch_bounds__(256,1) void k1_knn(const unsigned short* __restrict__ xhi,
                                                const unsigned short* __restrict__ xlo,
                                                const float* __restrict__ sq,
                                                int* __restrict__ cand)
{
    const int o    = ((blockIdx.x & 7) << 7) + (blockIdx.x >> 3);  // XCD swizzle: cloud's 32 blocks -> 1 XCD
    const int wave = threadIdx.x >> 6;
    const int lane = threadIdx.x & 63;
    const int j    = lane & 15;          // my row within wave tile
    const int quad = lane >> 4;          // column subset id
    const int rowglob = o*64 + wave*16 + j;
    const int rowloc  = rowglob & (NPTS-1);
    const int cbase   = (rowglob >> 11) << 11;     // cloud base point id

    // B-operand (row vectors), loaded once: dims quad*8.. per k-half
    short8v bhi[2], blo[2];
    #pragma unroll
    for (int kk = 0; kk < 2; ++kk) {
        const size_t off = (size_t)rowglob*CIN + quad*8 + kk*32;
        bhi[kk] = *reinterpret_cast<const short8v*>(xhi + off);
        blo[kk] = *reinterpret_cast<const short8v*>(xlo + off);
    }

    float ld[KSUB]; int li[KSUB];        // sorted desc: ld[0] = worst kept
    #pragma unroll
    for (int k = 0; k < KSUB; ++k) { ld[k] = INFINITY; li[k] = 0; }

    for (int it = 0; it < NPTS/16; ++it) {         // 128 col tiles of 16
        const int colb = it*16;                    // cloud-local col base
        // A-operand (col vectors): lane loads col point colb + j
        const size_t abase = (size_t)(cbase + colb + j)*CIN + quad*8;
        const short8v ahi0 = *reinterpret_cast<const short8v*>(xhi + abase);
        const short8v ahi1 = *reinterpret_cast<const short8v*>(xhi + abase + 32);
        const short8v alo0 = *reinterpret_cast<const short8v*>(xlo + abase);
        const short8v alo1 = *reinterpret_cast<const short8v*>(xlo + abase + 32);

        float4v acc0 = {0.f,0.f,0.f,0.f}, acc1 = {0.f,0.f,0.f,0.f};
        acc0 = __builtin_amdgcn_mfma_f32_16x16x32_bf16(ahi0, bhi[0], acc0, 0,0,0);
        acc0 = __builtin_amdgcn_mfma_f32_16x16x32_bf16(ahi0, blo[0], acc0, 0,0,0);
        acc0 = __builtin_amdgcn_mfma_f32_16x16x32_bf16(alo0, bhi[0], acc0, 0,0,0);
        acc1 = __builtin_amdgcn_mfma_f32_16x16x32_bf16(ahi1, bhi[1], acc1, 0,0,0);
        acc1 = __builtin_amdgcn_mfma_f32_16x16x32_bf16(ahi1, blo[1], acc1, 0,0,0);
        acc1 = __builtin_amdgcn_mfma_f32_16x16x32_bf16(alo1, bhi[1], acc1, 0,0,0);

        // C layout: lane holds cols i = quad*4 + r for row j  (swapped operands)
        const float4v sqv = *reinterpret_cast<const float4v*>(sq + cbase + colb + quad*4);
        #pragma unroll
        for (int r = 0; r < 4; ++r) {
            const int cl = colb + quad*4 + r;      // cloud-local col id
            float s = sqv[r] - 2.f*(acc0[r] + acc1[r]);
            if (cl == rowloc) s = INFINITY;        // self-exclusion
            if (s < ld[0]) {
                ld[0] = s; li[0] = cl;
                #pragma unroll
                for (int k = 0; k < KSUB-1; ++k) {
                    if (ld[k] < ld[k+1]) {
                        float td = ld[k]; ld[k] = ld[k+1]; ld[k+1] = td;
                        int   ti = li[k]; li[k] = li[k+1]; li[k+1] = ti;
                    }
                }
            }
        }
    }
    int* dst = cand + (size_t)rowglob*NCAND + quad*KSUB;
    #pragma unroll
    for (int k = 0; k < 4; ++k) {
        int4 w = { li[4*k+0], li[4*k+1], li[4*k+2], li[4*k+3] };
        *reinterpret_cast<int4*>(dst + 4*k) = w;
    }
}

// np.sum pairwise-8 replication for 64 squares (fp32, no FMA) — keep BIT-IDENTICAL.
__device__ __forceinline__ float np_sq64(const float* __restrict__ v)
{
    float r[8];
    #pragma unroll
    for (int j = 0; j < 8; ++j) r[j] = __fmul_rn(v[j], v[j]);
    #pragma unroll
    for (int i = 1; i < 8; ++i)
        #pragma unroll
        for (int j = 0; j < 8; ++j) r[j] = __fadd_rn(r[j], __fmul_rn(v[8*i+j], v[8*i+j]));
    return __fadd_rn(__fadd_rn(__fadd_rn(r[0],r[1]), __fadd_rn(r[2],r[3])),
                     __fadd_rn(__fadd_rn(r[4],r[5]), __fadd_rn(r[6],r[7])));
}

// ---------------- K2: wave-per-point, lane-per-candidate np-faithful exact rerank ----------------
__global__ void k2_refine(const float* __restrict__ x, const int* __restrict__ cand, int* __restrict__ nbr)
{
    const int w    = blockIdx.x * 4 + (threadIdx.x >> 6);   // point id
    const int lane = threadIdx.x & 63;
    const int b    = w >> 11;
    const float* xc = x + (size_t)b * NPTS * CIN;
    const float* xp = xc + (size_t)(w & (NPTS-1)) * CIN;

    float xpl[CIN];
    #pragma unroll
    for (int i = 0; i < CIN/4; ++i) {
        float4 v = *reinterpret_cast<const float4*>(xp + 4*i);
        xpl[4*i+0]=v.x; xpl[4*i+1]=v.y; xpl[4*i+2]=v.z; xpl[4*i+3]=v.w;
    }
    const float sqp = np_sq64(xpl);

    const int q = cand[(size_t)w * NCAND + lane];           // all 64 distinct by construction
    const float* xq = xc + (size_t)q * CIN;
    float r[8];
    float dot = 0.f;
    {
        float4 v0 = *reinterpret_cast<const float4*>(xq + 0);
        float4 v1 = *reinterpret_cast<const float4*>(xq + 4);
        float g[8] = {v0.x,v0.y,v0.z,v0.w,v1.x,v1.y,v1.z,v1.w};
        #pragma unroll
        for (int u = 0; u < 8; ++u) {
            r[u] = __fmul_rn(g[u], g[u]);
            dot  = __fadd_rn(dot, __fmul_rn(xpl[u], g[u]));
        }
    }
    #pragma unroll
    for (int i = 1; i < 8; ++i) {
        float4 v0 = *reinterpret_cast<const float4*>(xq + 8*i);
        float4 v1 = *reinterpret_cast<const float4*>(xq + 8*i + 4);
        float g[8] = {v0.x,v0.y,v0.z,v0.w,v1.x,v1.y,v1.z,v1.w};
        #pragma unroll
        for (int u = 0; u < 8; ++u) {
            r[u] = __fadd_rn(r[u], __fmul_rn(g[u], g[u]));
            dot  = __fadd_rn(dot, __fmul_rn(xpl[8*i+u], g[u]));
        }
    }
    const float sqq = __fadd_rn(__fadd_rn(__fadd_rn(r[0],r[1]), __fadd_rn(r[2],r[3])),
                                __fadd_rn(__fadd_rn(r[4],r[5]), __fadd_rn(r[6],r[7])));
    const float d = __fsub_rn(__fadd_rn(sqp, sqq), __fmul_rn(2.f, dot));

    int rank = 0;
    for (int s = 0; s < 64; ++s) {                 // exact rank with (d, idx) total order
        float dj = __shfl(d, s);
        int   qj = __shfl(q, s);
        rank += (dj < d || (dj == d && qj < q)) ? 1 : 0;
    }
    if (rank < KNN)
        nbr[(size_t)w * KNN + rank] = b * NPTS + q;
}

// ---------------- K3: scatter-max via float-as-int atomics ----------------
__global__ void k3_scatter(const float* __restrict__ x, const int* __restrict__ nbr, float* __restrict__ pooled)
{
    const int gtid = blockIdx.x * blockDim.x + threadIdx.x;
    const int c    = gtid >> 6;
    const int lane = threadIdx.x & 63;
    const float v  = x[(size_t)c * CIN + lane];
    const int   vi = __float_as_int(v);
    const unsigned vu = __float_as_uint(v);
    #pragma unroll
    for (int k = 0; k < KNN; ++k) {
        const int n = nbr[(size_t)c * KNN + k];
        float* addr = &pooled[(size_t)n * CIN + lane];
        if (v >= 0.f) atomicMax((int*)addr, vi);
        else          atomicMin((unsigned*)addr, vu);
    }
}

// ---------------- K4: y = pooled @ W^T + b ----------------
__global__ __launch_bounds__(256,2) void k4_linear(const float* __restrict__ pooled, const float* __restrict__ W,
                                                   const float* __restrict__ bias, float* __restrict__ y)
{
    __shared__ float wl[COUT*68];
    __shared__ float pl[64*68];
    const int t  = threadIdx.x;
    const int r0 = blockIdx.x * 64;
    for (int i = 0; i < (COUT*CIN)/256; ++i) {
        int linear = t + 256*i;
        int c = linear >> 6, k = linear & 63;
        wl[c*68 + k] = W[linear];
    }
    for (int i = 0; i < (64*CIN)/256; ++i) {
        int linear = t + 256*i;
        int r = linear >> 6, k = linear & 63;
        float v = pooled[(size_t)(r0 + r)*CIN + k];
        if (v != v) v = 0.f;                       // NaN marker = empty row -> 0
        pl[r*68 + k] = v;
    }
    __syncthreads();
    const int tx = t & 15;
    const int ty = t >> 4;
    float acc[4][8];
    #pragma unroll
    for (int j = 0; j < 8; ++j) {
        float bj = bias[tx + 16*j];
        #pragma unroll
        for (int i = 0; i < 4; ++i) acc[i][j] = bj;
    }
    for (int k = 0; k < CIN; k += 4) {
        float4 a[4], bb[8];
        #pragma unroll
        for (int i = 0; i < 4; ++i) a[i]  = *reinterpret_cast<const float4*>(&pl[(ty*4+i)*68 + k]);
        #pragma unroll
        for (int j = 0; j < 8; ++j) bb[j] = *reinterpret_cast<const float4*>(&wl[(tx+16*j)*68 + k]);
        #pragma unroll
        for (int i = 0; i < 4; ++i)
            #pragma unroll
            for (int j = 0; j < 8; ++j) {
                acc[i][j] = fmaf(a[i].x, bb[j].x, acc[i][j]);
                acc[i][j] = fmaf(a[i].y, bb[j].y, acc[i][j]);
                acc[i][j] = fmaf(a[i].z, bb[j].z, acc[i][j]);
                acc[i][j] = fmaf(a[i].w, bb[j].w, acc[i][j]);
            }
    }
    #pragma unroll
    for (int i = 0; i < 4; ++i) {
        float* dst = y + (size_t)(r0 + ty*4 + i) * COUT;
        #pragma unroll
        for (int j = 0; j < 8; ++j) dst[tx + 16*j] = acc[i][j];
    }
}

// ---------------- K5: per-channel sum / sumsq (fp64) ----------------
__global__ void k5_stats(const float* __restrict__ y, double* __restrict__ sums)
{
    __shared__ double red[512];
    const int t    = threadIdx.x;
    const int ch   = t & 127;
    const int half = t >> 7;
    const size_t base = (size_t)blockIdx.x * 256;
    double s = 0.0, ss = 0.0;
    for (int r = 0; r < 128; ++r) {
        double v = (double)y[(base + (size_t)half*128 + r) * COUT + ch];
        s += v; ss += v*v;
    }
    red[t] = s; red[256 + t] = ss;
    __syncthreads();
    if (half == 0) {
        atomicAdd(&sums[ch],        s  + red[128 + ch]);
        atomicAdd(&sums[COUT + ch], ss + red[256 + 128 + ch]);
    }
}

// ---------------- K6: BN scale/shift ----------------
__global__ void k6_bnparam(const double* __restrict__ sums, const float* __restrict__ gamma,
                           const float* __restrict__ beta, float* __restrict__ scsh)
{
    const int t = threadIdx.x;
    const double mean = sums[t] * (1.0/NTOT);
    const double var  = sums[COUT + t] * (1.0/NTOT) - mean*mean;
    const float inv   = (float)rsqrt(var + 1e-5);
    const float sc    = inv * gamma[t];
    scsh[t]        = sc;
    scsh[COUT + t] = beta[t] - (float)mean * sc;
}

// ---------------- K7: out = relu(y*scale + shift) ----------------
__global__ void k7_bnrelu(const float* __restrict__ y, const float* __restrict__ scsh, float* __restrict__ out)
{
    const int g    = blockIdx.x * blockDim.x + threadIdx.x;
    const int base = g * 4;
    float4 v = *reinterpret_cast<const float4*>(y + base);
    const int ch = base & (COUT-1);
    float4 o;
    o.x = fmaxf(0.f, fmaf(v.x, scsh[ch+0], scsh[COUT+ch+0]));
    o.y = fmaxf(0.f, fmaf(v.y, scsh[ch+1], scsh[COUT+ch+1]));
    o.z = fmaxf(0.f, fmaf(v.z, scsh[ch+2], scsh[COUT+ch+2]));
    o.w = fmaxf(0.f, fmaf(v.w, scsh[ch+3], scsh[COUT+ch+3]));
    *reinterpret_cast<float4*>(out + base) = o;
}

extern "C" void kernel_launch(void* const* d_in, const int* in_sizes, int n_in,
                              void* d_out, int out_size, void* d_ws, size_t ws_size,
                              hipStream_t stream)
{
    const float* x     = (const float*)d_in[0];
    const float* W     = (const float*)d_in[2];
    const float* bias  = (const float*)d_in[3];
    const float* gamma = (const float*)d_in[4];
    const float* beta  = (const float*)d_in[5];
    float* out = (float*)d_out;

    // Workspace (aliasing by liveness; stream order makes each safe):
    //  [0 .. 8M)    xhi        (k0 out, k1 in)   -> pooled (memset after k2)
    //  [8 ..16M)    xlo        (k0 out, k1 in)   -> pooled tail
    //  [16..32M)    cand       (k1 out, k2 in)   -> y[0..16M) (k4 writes after)
    //  [32..36M)    nbr        (k2 out, k3 in)   -> y[16..20M)
    //  [16..48M)    y          (k4 out; k5/k7 in)
    //  [48M..)      sq, sums, scsh
    char* ws = (char*)d_ws;
    unsigned short* xhi = (unsigned short*)ws;                       // NTOT*64 u16
    unsigned short* xlo = (unsigned short*)(ws + (size_t)NTOT*CIN*2);
    float*  pooled = (float*)ws;                                     // NTOT*64 f32 (aliases xhi/xlo)
    int*    cand   = (int*)(ws + (size_t)NTOT*CIN*4);                // NTOT*64 int
    float*  y      = (float*)(ws + (size_t)NTOT*CIN*4);              // NTOT*128 f32 (aliases cand+nbr)
    int*    nbr    = (int*)(ws + (size_t)NTOT*(CIN+CIN)*4);          // NTOT*16 int
    float*  sq     = (float*)(ws + (size_t)NTOT*(CIN+COUT)*4);       // NTOT f32
    double* sums   = (double*)(ws + (size_t)NTOT*(CIN+COUT+1)*4);    // 2*COUT f64
    float*  scsh   = (float*)((char*)sums + 2*COUT*sizeof(double));

    k0_prep  <<<NTOT/256,   256, 0, stream>>>(x, xhi, xlo, sq);
    k1_knn   <<<NTOT/64,    256, 0, stream>>>(xhi, xlo, sq, cand);
    k2_refine<<<NTOT/4,     256, 0, stream>>>(x, cand, nbr);

    hipMemsetAsync(pooled, 0xFF, (size_t)NTOT*CIN*4, stream);   // NaN marker (xhi/xlo dead)
    hipMemsetAsync(sums, 0, 2*COUT*sizeof(double), stream);

    k3_scatter<<<NTOT/4,  256, 0, stream>>>(x, nbr, pooled);
    k4_linear <<<NTOT/64, 256, 0, stream>>>(pooled, W, bias, y);
    k5_stats  <<<NTOT/256,256, 0, stream>>>(y, sums);
    k6_bnparam<<<1,      COUT, 0, stream>>>(sums, gamma, beta, scsh);
    k7_bnrelu <<<(NTOT*COUT/4)/256, 256, 0, stream>>>(y, scsh, out);
}

// Round 6
// 951.143 us; speedup vs baseline: 297.3943x; 1.1793x over previous
//
#include <hip/hip_runtime.h>
#include <hip/hip_bf16.h>
#include <math.h>

#define NPTS 2048
#define NCLOUD 32
#define NTOT (NPTS*NCLOUD)
#define CIN 64
#define COUT 128
#define KNN 16
#define KSUB 16            // per-lane-subset kept candidates (16 = superset guarantee)
#define NCAND 64           // 4 subsets * 16

typedef __attribute__((ext_vector_type(8))) short short8v;   // 8 bf16 (4 VGPR)
typedef __attribute__((ext_vector_type(4))) float float4v;   // 4 fp32

__device__ __forceinline__ unsigned short f2bf(float f) {    // RNE float->bf16
    unsigned u = __float_as_uint(f);
    return (unsigned short)((u + 0x7fffu + ((u >> 16) & 1u)) >> 16);
}
__device__ __forceinline__ float bf2f(unsigned short h) {
    return __uint_as_float(((unsigned)h) << 16);
}

// ---------------- K0: bf16 hi/lo planes + |q|^2 (fp32, ranking-only) ----------------
__global__ void k0_prep(const float* __restrict__ x, unsigned short* __restrict__ xhi,
                        unsigned short* __restrict__ xlo, float* __restrict__ sq)
{
    const int p = blockIdx.x * 256 + threadIdx.x;
    const float* src = x + (size_t)p * CIN;
    float s = 0.f;
    #pragma unroll
    for (int i = 0; i < 8; ++i) {
        float4 v0 = *reinterpret_cast<const float4*>(src + 8*i);
        float4 v1 = *reinterpret_cast<const float4*>(src + 8*i + 4);
        float e[8] = {v0.x,v0.y,v0.z,v0.w,v1.x,v1.y,v1.z,v1.w};
        short8v h, l;
        #pragma unroll
        for (int u = 0; u < 8; ++u) {
            unsigned short hb = f2bf(e[u]);
            h[u] = (short)hb;
            l[u] = (short)f2bf(e[u] - bf2f(hb));
            s = fmaf(e[u], e[u], s);
        }
        *reinterpret_cast<short8v*>(xhi + (size_t)p*CIN + 8*i) = h;
        *reinterpret_cast<short8v*>(xlo + (size_t)p*CIN + 8*i) = l;
    }
    sq[p] = s;
}

// ---------------- K1: MFMA swapped-operand KNN + branchless packed-u32 top-16 ----------------
// Wave owns 16 rows (j=lane&15); quad (lane>>4) covers column subset {quad*4+r + 16*it}.
// Selection key: monotone(float) with 11-bit col id packed in low mantissa bits.
// Truncation error ~0.03 << subset-boundary tolerance (~1.0). Self NOT excluded here
// (occupies one slot; superset broken only if all 16 true nbrs in one subset, P~1e-9);
// k2 excludes q==p exactly.
__global__ __launch_bounds__(256,1) void k1_knn(const unsigned short* __restrict__ xhi,
                                                const unsigned short* __restrict__ xlo,
                                                const float* __restrict__ sq,
                                                int* __restrict__ cand)
{
    const int o    = ((blockIdx.x & 7) << 7) + (blockIdx.x >> 3);  // XCD swizzle
    const int wave = threadIdx.x >> 6;
    const int lane = threadIdx.x & 63;
    const int j    = lane & 15;
    const int quad = lane >> 4;
    const int rowglob = o*64 + wave*16 + j;
    const int cbase   = (rowglob >> 11) << 11;     // cloud base point id

    short8v bhi[2], blo[2];
    #pragma unroll
    for (int kk = 0; kk < 2; ++kk) {
        const size_t off = (size_t)rowglob*CIN + quad*8 + kk*32;
        bhi[kk] = *reinterpret_cast<const short8v*>(xhi + off);
        blo[kk] = *reinterpret_cast<const short8v*>(xlo + off);
    }

    unsigned kd[KSUB];                 // sorted DESC: kd[0] = worst kept
    #pragma unroll
    for (int k = 0; k < KSUB; ++k) kd[k] = 0xFFFFFFFFu;

    for (int it = 0; it < NPTS/16; ++it) {
        const int colb = it*16;
        const size_t abase = (size_t)(cbase + colb + j)*CIN + quad*8;
        const short8v ahi0 = *reinterpret_cast<const short8v*>(xhi + abase);
        const short8v ahi1 = *reinterpret_cast<const short8v*>(xhi + abase + 32);
        const short8v alo0 = *reinterpret_cast<const short8v*>(xlo + abase);
        const short8v alo1 = *reinterpret_cast<const short8v*>(xlo + abase + 32);

        float4v acc0 = {0.f,0.f,0.f,0.f}, acc1 = {0.f,0.f,0.f,0.f};
        acc0 = __builtin_amdgcn_mfma_f32_16x16x32_bf16(ahi0, bhi[0], acc0, 0,0,0);
        acc0 = __builtin_amdgcn_mfma_f32_16x16x32_bf16(ahi0, blo[0], acc0, 0,0,0);
        acc0 = __builtin_amdgcn_mfma_f32_16x16x32_bf16(alo0, bhi[0], acc0, 0,0,0);
        acc1 = __builtin_amdgcn_mfma_f32_16x16x32_bf16(ahi1, bhi[1], acc1, 0,0,0);
        acc1 = __builtin_amdgcn_mfma_f32_16x16x32_bf16(ahi1, blo[1], acc1, 0,0,0);
        acc1 = __builtin_amdgcn_mfma_f32_16x16x32_bf16(alo1, bhi[1], acc1, 0,0,0);

        const float4v sqv = *reinterpret_cast<const float4v*>(sq + cbase + colb + quad*4);
        const unsigned idxbase = (unsigned)(colb + quad*4);
        #pragma unroll
        for (int r = 0; r < 4; ++r) {
            const float s = fmaf(-2.f, acc0[r] + acc1[r], sqv[r]);
            unsigned u = __float_as_uint(s);
            u ^= (unsigned)(((int)u >> 31) | 0x80000000);   // monotone float->uint
            const unsigned key = (u & 0xFFFFF800u) | (idxbase + r);
            kd[0] = min(kd[0], key);                        // branchless insert
            #pragma unroll
            for (int st = 0; st < KSUB-1; ++st) {           // one bubble pass (desc)
                const unsigned hi = max(kd[st], kd[st+1]);
                const unsigned lo = min(kd[st], kd[st+1]);
                kd[st] = hi; kd[st+1] = lo;
            }
        }
    }
    int* dst = cand + (size_t)rowglob*NCAND + quad*KSUB;
    #pragma unroll
    for (int k = 0; k < 4; ++k) {
        int4 w = { (int)(kd[4*k+0] & 0x7FFu), (int)(kd[4*k+1] & 0x7FFu),
                   (int)(kd[4*k+2] & 0x7FFu), (int)(kd[4*k+3] & 0x7FFu) };
        *reinterpret_cast<int4*>(dst + 4*k) = w;
    }
}

// np.sum pairwise-8 replication for 64 squares (fp32, no FMA) — keep BIT-IDENTICAL.
__device__ __forceinline__ float np_sq64(const float* __restrict__ v)
{
    float r[8];
    #pragma unroll
    for (int j = 0; j < 8; ++j) r[j] = __fmul_rn(v[j], v[j]);
    #pragma unroll
    for (int i = 1; i < 8; ++i)
        #pragma unroll
        for (int j = 0; j < 8; ++j) r[j] = __fadd_rn(r[j], __fmul_rn(v[8*i+j], v[8*i+j]));
    return __fadd_rn(__fadd_rn(__fadd_rn(r[0],r[1]), __fadd_rn(r[2],r[3])),
                     __fadd_rn(__fadd_rn(r[4],r[5]), __fadd_rn(r[6],r[7])));
}

// ---------------- K2: wave-per-point, lane-per-candidate np-faithful exact rerank ----------------
__global__ void k2_refine(const float* __restrict__ x, const int* __restrict__ cand, int* __restrict__ nbr)
{
    const int w    = blockIdx.x * 4 + (threadIdx.x >> 6);   // point id
    const int lane = threadIdx.x & 63;
    const int b    = w >> 11;
    const int ploc = w & (NPTS-1);
    const float* xc = x + (size_t)b * NPTS * CIN;
    const float* xp = xc + (size_t)ploc * CIN;

    float xpl[CIN];
    #pragma unroll
    for (int i = 0; i < CIN/4; ++i) {
        float4 v = *reinterpret_cast<const float4*>(xp + 4*i);
        xpl[4*i+0]=v.x; xpl[4*i+1]=v.y; xpl[4*i+2]=v.z; xpl[4*i+3]=v.w;
    }
    const float sqp = np_sq64(xpl);

    const int q = cand[(size_t)w * NCAND + lane];
    const float* xq = xc + (size_t)q * CIN;
    float r[8];
    float dot = 0.f;
    {
        float4 v0 = *reinterpret_cast<const float4*>(xq + 0);
        float4 v1 = *reinterpret_cast<const float4*>(xq + 4);
        float g[8] = {v0.x,v0.y,v0.z,v0.w,v1.x,v1.y,v1.z,v1.w};
        #pragma unroll
        for (int u = 0; u < 8; ++u) {
            r[u] = __fmul_rn(g[u], g[u]);
            dot  = __fadd_rn(dot, __fmul_rn(xpl[u], g[u]));
        }
    }
    #pragma unroll
    for (int i = 1; i < 8; ++i) {
        float4 v0 = *reinterpret_cast<const float4*>(xq + 8*i);
        float4 v1 = *reinterpret_cast<const float4*>(xq + 8*i + 4);
        float g[8] = {v0.x,v0.y,v0.z,v0.w,v1.x,v1.y,v1.z,v1.w};
        #pragma unroll
        for (int u = 0; u < 8; ++u) {
            r[u] = __fadd_rn(r[u], __fmul_rn(g[u], g[u]));
            dot  = __fadd_rn(dot, __fmul_rn(xpl[8*i+u], g[u]));
        }
    }
    const float sqq = __fadd_rn(__fadd_rn(__fadd_rn(r[0],r[1]), __fadd_rn(r[2],r[3])),
                                __fadd_rn(__fadd_rn(r[4],r[5]), __fadd_rn(r[6],r[7])));
    float d = __fsub_rn(__fadd_rn(sqp, sqq), __fmul_rn(2.f, dot));
    if (q == ploc) d = INFINITY;                    // self-exclusion (exact, loop=False)

    int rank = 0;
    for (int s = 0; s < 64; ++s) {                  // exact rank with (d, idx) total order
        float dj = __shfl(d, s);
        int   qj = __shfl(q, s);
        rank += (dj < d || (dj == d && qj < q)) ? 1 : 0;
    }
    if (rank < KNN)
        nbr[(size_t)w * KNN + rank] = b * NPTS + q;
}

// ---------------- K3: scatter-max via float-as-int atomics ----------------
__global__ void k3_scatter(const float* __restrict__ x, const int* __restrict__ nbr, float* __restrict__ pooled)
{
    const int gtid = blockIdx.x * blockDim.x + threadIdx.x;
    const int c    = gtid >> 6;
    const int lane = threadIdx.x & 63;
    const float v  = x[(size_t)c * CIN + lane];
    const int   vi = __float_as_int(v);
    const unsigned vu = __float_as_uint(v);
    #pragma unroll
    for (int k = 0; k < KNN; ++k) {
        const int n = nbr[(size_t)c * KNN + k];
        float* addr = &pooled[(size_t)n * CIN + lane];
        if (v >= 0.f) atomicMax((int*)addr, vi);
        else          atomicMin((unsigned*)addr, vu);
    }
}

// ---------------- K4: y = pooled @ W^T + b ----------------
__global__ __launch_bounds__(256,2) void k4_linear(const float* __restrict__ pooled, const float* __restrict__ W,
                                                   const float* __restrict__ bias, float* __restrict__ y)
{
    __shared__ float wl[COUT*68];
    __shared__ float pl[64*68];
    const int t  = threadIdx.x;
    const int r0 = blockIdx.x * 64;
    for (int i = 0; i < (COUT*CIN)/256; ++i) {
        int linear = t + 256*i;
        int c = linear >> 6, k = linear & 63;
        wl[c*68 + k] = W[linear];
    }
    for (int i = 0; i < (64*CIN)/256; ++i) {
        int linear = t + 256*i;
        int r = linear >> 6, k = linear & 63;
        float v = pooled[(size_t)(r0 + r)*CIN + k];
        if (v != v) v = 0.f;                       // NaN marker = empty row -> 0
        pl[r*68 + k] = v;
    }
    __syncthreads();
    const int tx = t & 15;
    const int ty = t >> 4;
    float acc[4][8];
    #pragma unroll
    for (int j = 0; j < 8; ++j) {
        float bj = bias[tx + 16*j];
        #pragma unroll
        for (int i = 0; i < 4; ++i) acc[i][j] = bj;
    }
    for (int k = 0; k < CIN; k += 4) {
        float4 a[4], bb[8];
        #pragma unroll
        for (int i = 0; i < 4; ++i) a[i]  = *reinterpret_cast<const float4*>(&pl[(ty*4+i)*68 + k]);
        #pragma unroll
        for (int j = 0; j < 8; ++j) bb[j] = *reinterpret_cast<const float4*>(&wl[(tx+16*j)*68 + k]);
        #pragma unroll
        for (int i = 0; i < 4; ++i)
            #pragma unroll
            for (int j = 0; j < 8; ++j) {
                acc[i][j] = fmaf(a[i].x, bb[j].x, acc[i][j]);
                acc[i][j] = fmaf(a[i].y, bb[j].y, acc[i][j]);
                acc[i][j] = fmaf(a[i].z, bb[j].z, acc[i][j]);
                acc[i][j] = fmaf(a[i].w, bb[j].w, acc[i][j]);
            }
    }
    #pragma unroll
    for (int i = 0; i < 4; ++i) {
        float* dst = y + (size_t)(r0 + ty*4 + i) * COUT;
        #pragma unroll
        for (int j = 0; j < 8; ++j) dst[tx + 16*j] = acc[i][j];
    }
}

// ---------------- K5: per-channel sum / sumsq (fp64), 2048 blocks x 32 rows ----------------
__global__ void k5_stats(const float* __restrict__ y, double* __restrict__ sums)
{
    __shared__ double red[512];
    const int t    = threadIdx.x;
    const int ch   = t & 127;
    const int half = t >> 7;
    const size_t base = (size_t)blockIdx.x * 32;
    double s = 0.0, ss = 0.0;
    for (int r = 0; r < 16; ++r) {
        double v = (double)y[(base + (size_t)half*16 + r) * COUT + ch];
        s += v; ss += v*v;
    }
    red[t] = s; red[256 + t] = ss;
    __syncthreads();
    if (half == 0) {
        atomicAdd(&sums[ch],        s  + red[128 + ch]);
        atomicAdd(&sums[COUT + ch], ss + red[256 + 128 + ch]);
    }
}

// ---------------- K6: BN scale/shift ----------------
__global__ void k6_bnparam(const double* __restrict__ sums, const float* __restrict__ gamma,
                           const float* __restrict__ beta, float* __restrict__ scsh)
{
    const int t = threadIdx.x;
    const double mean = sums[t] * (1.0/NTOT);
    const double var  = sums[COUT + t] * (1.0/NTOT) - mean*mean;
    const float inv   = (float)rsqrt(var + 1e-5);
    const float sc    = inv * gamma[t];
    scsh[t]        = sc;
    scsh[COUT + t] = beta[t] - (float)mean * sc;
}

// ---------------- K7: out = relu(y*scale + shift) ----------------
__global__ void k7_bnrelu(const float* __restrict__ y, const float* __restrict__ scsh, float* __restrict__ out)
{
    const int g    = blockIdx.x * blockDim.x + threadIdx.x;
    const int base = g * 4;
    float4 v = *reinterpret_cast<const float4*>(y + base);
    const int ch = base & (COUT-1);
    float4 o;
    o.x = fmaxf(0.f, fmaf(v.x, scsh[ch+0], scsh[COUT+ch+0]));
    o.y = fmaxf(0.f, fmaf(v.y, scsh[ch+1], scsh[COUT+ch+1]));
    o.z = fmaxf(0.f, fmaf(v.z, scsh[ch+2], scsh[COUT+ch+2]));
    o.w = fmaxf(0.f, fmaf(v.w, scsh[ch+3], scsh[COUT+ch+3]));
    *reinterpret_cast<float4*>(out + base) = o;
}

extern "C" void kernel_launch(void* const* d_in, const int* in_sizes, int n_in,
                              void* d_out, int out_size, void* d_ws, size_t ws_size,
                              hipStream_t stream)
{
    const float* x     = (const float*)d_in[0];
    const float* W     = (const float*)d_in[2];
    const float* bias  = (const float*)d_in[3];
    const float* gamma = (const float*)d_in[4];
    const float* beta  = (const float*)d_in[5];
    float* out = (float*)d_out;

    // Workspace (aliasing by liveness; stream order makes each safe)
    char* ws = (char*)d_ws;
    unsigned short* xhi = (unsigned short*)ws;                       // NTOT*64 u16
    unsigned short* xlo = (unsigned short*)(ws + (size_t)NTOT*CIN*2);
    float*  pooled = (float*)ws;                                     // NTOT*64 f32 (aliases xhi/xlo)
    int*    cand   = (int*)(ws + (size_t)NTOT*CIN*4);                // NTOT*64 int
    float*  y      = (float*)(ws + (size_t)NTOT*CIN*4);              // NTOT*128 f32 (aliases cand+nbr)
    int*    nbr    = (int*)(ws + (size_t)NTOT*(CIN+CIN)*4);          // NTOT*16 int
    float*  sq     = (float*)(ws + (size_t)NTOT*(CIN+COUT)*4);       // NTOT f32
    double* sums   = (double*)(ws + (size_t)NTOT*(CIN+COUT+1)*4);    // 2*COUT f64
    float*  scsh   = (float*)((char*)sums + 2*COUT*sizeof(double));

    k0_prep  <<<NTOT/256,   256, 0, stream>>>(x, xhi, xlo, sq);
    k1_knn   <<<NTOT/64,    256, 0, stream>>>(xhi, xlo, sq, cand);
    k2_refine<<<NTOT/4,     256, 0, stream>>>(x, cand, nbr);

    hipMemsetAsync(pooled, 0xFF, (size_t)NTOT*CIN*4, stream);   // NaN marker (xhi/xlo dead)
    hipMemsetAsync(sums, 0, 2*COUT*sizeof(double), stream);

    k3_scatter<<<NTOT/4,  256, 0, stream>>>(x, nbr, pooled);
    k4_linear <<<NTOT/64, 256, 0, stream>>>(pooled, W, bias, y);
    k5_stats  <<<NTOT/32, 256, 0, stream>>>(y, sums);
    k6_bnparam<<<1,      COUT, 0, stream>>>(sums, gamma, beta, scsh);
    k7_bnrelu <<<(NTOT*COUT/4)/256, 256, 0, stream>>>(y, scsh, out);
}

// Round 7
// 823.893 us; speedup vs baseline: 343.3267x; 1.1544x over previous
//
#include <hip/hip_runtime.h>
#include <hip/hip_bf16.h>
#include <math.h>

#define NPTS 2048
#define NCLOUD 32
#define NTOT (NPTS*NCLOUD)
#define CIN 64
#define COUT 128
#define KNN 16
#define KSUB 16            // per-lane-subset kept candidates (16 = superset guarantee)
#define NCAND 64           // 4 subsets * 16

typedef __attribute__((ext_vector_type(8))) short short8v;   // 8 bf16 (4 VGPR)
typedef __attribute__((ext_vector_type(4))) float float4v;   // 4 fp32

__device__ __forceinline__ unsigned short f2bf(float f) {    // RNE float->bf16
    unsigned u = __float_as_uint(f);
    return (unsigned short)((u + 0x7fffu + ((u >> 16) & 1u)) >> 16);
}
__device__ __forceinline__ float bf2f(unsigned short h) {
    return __uint_as_float(((unsigned)h) << 16);
}

// ---------------- K0: bf16 hi/lo planes + |q|^2 (fp32, ranking-only) ----------------
__global__ void k0_prep(const float* __restrict__ x, unsigned short* __restrict__ xhi,
                        unsigned short* __restrict__ xlo, float* __restrict__ sq)
{
    const int p = blockIdx.x * 256 + threadIdx.x;
    const float* src = x + (size_t)p * CIN;
    float s = 0.f;
    #pragma unroll
    for (int i = 0; i < 8; ++i) {
        float4 v0 = *reinterpret_cast<const float4*>(src + 8*i);
        float4 v1 = *reinterpret_cast<const float4*>(src + 8*i + 4);
        float e[8] = {v0.x,v0.y,v0.z,v0.w,v1.x,v1.y,v1.z,v1.w};
        short8v h, l;
        #pragma unroll
        for (int u = 0; u < 8; ++u) {
            unsigned short hb = f2bf(e[u]);
            h[u] = (short)hb;
            l[u] = (short)f2bf(e[u] - bf2f(hb));
            s = fmaf(e[u], e[u], s);
        }
        *reinterpret_cast<short8v*>(xhi + (size_t)p*CIN + 8*i) = h;
        *reinterpret_cast<short8v*>(xlo + (size_t)p*CIN + 8*i) = l;
    }
    sq[p] = s;
}

// ---------------- K1: MFMA swapped-operand KNN + branchless packed-u32 top-16 ----------------
__global__ __launch_bounds__(256,1) void k1_knn(const unsigned short* __restrict__ xhi,
                                                const unsigned short* __restrict__ xlo,
                                                const float* __restrict__ sq,
                                                int* __restrict__ cand)
{
    const int o    = ((blockIdx.x & 7) << 7) + (blockIdx.x >> 3);  // XCD swizzle
    const int wave = threadIdx.x >> 6;
    const int lane = threadIdx.x & 63;
    const int j    = lane & 15;
    const int quad = lane >> 4;
    const int rowglob = o*64 + wave*16 + j;
    const int cbase   = (rowglob >> 11) << 11;     // cloud base point id

    short8v bhi[2], blo[2];
    #pragma unroll
    for (int kk = 0; kk < 2; ++kk) {
        const size_t off = (size_t)rowglob*CIN + quad*8 + kk*32;
        bhi[kk] = *reinterpret_cast<const short8v*>(xhi + off);
        blo[kk] = *reinterpret_cast<const short8v*>(xlo + off);
    }

    unsigned kd[KSUB];                 // sorted DESC: kd[0] = worst kept
    #pragma unroll
    for (int k = 0; k < KSUB; ++k) kd[k] = 0xFFFFFFFFu;

    for (int it = 0; it < NPTS/16; ++it) {
        const int colb = it*16;
        const size_t abase = (size_t)(cbase + colb + j)*CIN + quad*8;
        const short8v ahi0 = *reinterpret_cast<const short8v*>(xhi + abase);
        const short8v ahi1 = *reinterpret_cast<const short8v*>(xhi + abase + 32);
        const short8v alo0 = *reinterpret_cast<const short8v*>(xlo + abase);
        const short8v alo1 = *reinterpret_cast<const short8v*>(xlo + abase + 32);

        float4v acc0 = {0.f,0.f,0.f,0.f}, acc1 = {0.f,0.f,0.f,0.f};
        acc0 = __builtin_amdgcn_mfma_f32_16x16x32_bf16(ahi0, bhi[0], acc0, 0,0,0);
        acc0 = __builtin_amdgcn_mfma_f32_16x16x32_bf16(ahi0, blo[0], acc0, 0,0,0);
        acc0 = __builtin_amdgcn_mfma_f32_16x16x32_bf16(alo0, bhi[0], acc0, 0,0,0);
        acc1 = __builtin_amdgcn_mfma_f32_16x16x32_bf16(ahi1, bhi[1], acc1, 0,0,0);
        acc1 = __builtin_amdgcn_mfma_f32_16x16x32_bf16(ahi1, blo[1], acc1, 0,0,0);
        acc1 = __builtin_amdgcn_mfma_f32_16x16x32_bf16(alo1, bhi[1], acc1, 0,0,0);

        const float4v sqv = *reinterpret_cast<const float4v*>(sq + cbase + colb + quad*4);
        const unsigned idxbase = (unsigned)(colb + quad*4);
        #pragma unroll
        for (int r = 0; r < 4; ++r) {
            const float s = fmaf(-2.f, acc0[r] + acc1[r], sqv[r]);
            unsigned u = __float_as_uint(s);
            u ^= (unsigned)(((int)u >> 31) | 0x80000000);   // monotone float->uint
            const unsigned key = (u & 0xFFFFF800u) | (idxbase + r);
            kd[0] = min(kd[0], key);                        // branchless insert
            #pragma unroll
            for (int st = 0; st < KSUB-1; ++st) {           // one bubble pass (desc)
                const unsigned hi = max(kd[st], kd[st+1]);
                const unsigned lo = min(kd[st], kd[st+1]);
                kd[st] = hi; kd[st+1] = lo;
            }
        }
    }
    int* dst = cand + (size_t)rowglob*NCAND + quad*KSUB;
    #pragma unroll
    for (int k = 0; k < 4; ++k) {
        int4 w = { (int)(kd[4*k+0] & 0x7FFu), (int)(kd[4*k+1] & 0x7FFu),
                   (int)(kd[4*k+2] & 0x7FFu), (int)(kd[4*k+3] & 0x7FFu) };
        *reinterpret_cast<int4*>(dst + 4*k) = w;
    }
}

// np.sum pairwise-8 replication for 64 squares (fp32, no FMA) — keep BIT-IDENTICAL.
__device__ __forceinline__ float np_sq64(const float* __restrict__ v)
{
    float r[8];
    #pragma unroll
    for (int j = 0; j < 8; ++j) r[j] = __fmul_rn(v[j], v[j]);
    #pragma unroll
    for (int i = 1; i < 8; ++i)
        #pragma unroll
        for (int j = 0; j < 8; ++j) r[j] = __fadd_rn(r[j], __fmul_rn(v[8*i+j], v[8*i+j]));
    return __fadd_rn(__fadd_rn(__fadd_rn(r[0],r[1]), __fadd_rn(r[2],r[3])),
                     __fadd_rn(__fadd_rn(r[4],r[5]), __fadd_rn(r[6],r[7])));
}

// ---------------- K2: wave-per-point exact rerank + in-degree count ----------------
__global__ void k2_refine(const float* __restrict__ x, const int* __restrict__ cand,
                          int* __restrict__ nbr, int* __restrict__ deg)
{
    const int w    = blockIdx.x * 4 + (threadIdx.x >> 6);   // point id
    const int lane = threadIdx.x & 63;
    const int b    = w >> 11;
    const int ploc = w & (NPTS-1);
    const float* xc = x + (size_t)b * NPTS * CIN;
    const float* xp = xc + (size_t)ploc * CIN;

    float xpl[CIN];
    #pragma unroll
    for (int i = 0; i < CIN/4; ++i) {
        float4 v = *reinterpret_cast<const float4*>(xp + 4*i);
        xpl[4*i+0]=v.x; xpl[4*i+1]=v.y; xpl[4*i+2]=v.z; xpl[4*i+3]=v.w;
    }
    const float sqp = np_sq64(xpl);

    const int q = cand[(size_t)w * NCAND + lane];
    const float* xq = xc + (size_t)q * CIN;
    float r[8];
    float dot = 0.f;
    {
        float4 v0 = *reinterpret_cast<const float4*>(xq + 0);
        float4 v1 = *reinterpret_cast<const float4*>(xq + 4);
        float g[8] = {v0.x,v0.y,v0.z,v0.w,v1.x,v1.y,v1.z,v1.w};
        #pragma unroll
        for (int u = 0; u < 8; ++u) {
            r[u] = __fmul_rn(g[u], g[u]);
            dot  = __fadd_rn(dot, __fmul_rn(xpl[u], g[u]));
        }
    }
    #pragma unroll
    for (int i = 1; i < 8; ++i) {
        float4 v0 = *reinterpret_cast<const float4*>(xq + 8*i);
        float4 v1 = *reinterpret_cast<const float4*>(xq + 8*i + 4);
        float g[8] = {v0.x,v0.y,v0.z,v0.w,v1.x,v1.y,v1.z,v1.w};
        #pragma unroll
        for (int u = 0; u < 8; ++u) {
            r[u] = __fadd_rn(r[u], __fmul_rn(g[u], g[u]));
            dot  = __fadd_rn(dot, __fmul_rn(xpl[8*i+u], g[u]));
        }
    }
    const float sqq = __fadd_rn(__fadd_rn(__fadd_rn(r[0],r[1]), __fadd_rn(r[2],r[3])),
                                __fadd_rn(__fadd_rn(r[4],r[5]), __fadd_rn(r[6],r[7])));
    float d = __fsub_rn(__fadd_rn(sqp, sqq), __fmul_rn(2.f, dot));
    if (q == ploc) d = INFINITY;                    // self-exclusion (exact, loop=False)

    int rank = 0;
    for (int s = 0; s < 64; ++s) {                  // exact rank with (d, idx) total order
        float dj = __shfl(d, s);
        int   qj = __shfl(q, s);
        rank += (dj < d || (dj == d && qj < q)) ? 1 : 0;
    }
    if (rank < KNN) {
        const int n = b * NPTS + q;
        nbr[(size_t)w * KNN + rank] = n;
        atomicAdd(&deg[n], 1);                      // in-degree for CSR
    }
}

// ---------------- K3s: exclusive prefix scan of deg -> rowstart & wcur (single block) ----------------
__global__ void k3_scan(const int* __restrict__ deg, int* __restrict__ rowstart, int* __restrict__ wcur)
{
    __shared__ int part[256];
    const int t = threadIdx.x;
    int s = 0;
    int loc[256/1];                                  // each thread: 256 entries
    #pragma unroll 4
    for (int i = 0; i < 256; ++i) { loc[i] = s; s += deg[t*256 + i]; }
    part[t] = s;
    __syncthreads();
    // LDS exclusive scan of 256 partials (single thread — tiny)
    __shared__ int base[257];
    if (t == 0) {
        int acc = 0;
        for (int i = 0; i < 256; ++i) { base[i] = acc; acc += part[i]; }
        base[256] = acc;
    }
    __syncthreads();
    const int b0 = base[t];
    #pragma unroll 4
    for (int i = 0; i < 256; ++i) {
        const int v = b0 + loc[i];
        rowstart[t*256 + i] = v;
        wcur[t*256 + i] = v;
    }
    if (t == 0) rowstart[NTOT] = base[256];
}

// ---------------- K3a: place edges into reverse lists (counter atomics only) ----------------
__global__ void k3_place(const int* __restrict__ nbr, int* __restrict__ wcur, int* __restrict__ rev)
{
    const int e = blockIdx.x * 256 + threadIdx.x;    // edge id
    const int c = e >> 4;                            // center (global point id)
    const int n = nbr[e];                            // neighbor (global point id)
    const int pos = atomicAdd(&wcur[n], 1);
    rev[pos] = c;
}

// ---------------- K3g: gather-max pooled[n] = max over rev(n) of x[c]; empty -> 0 ----------------
__global__ void k3_gather(const float* __restrict__ x, const int* __restrict__ rowstart,
                          const int* __restrict__ rev, float* __restrict__ pooled)
{
    const int n    = blockIdx.x * 4 + (threadIdx.x >> 6);   // point id, one wave each
    const int lane = threadIdx.x & 63;                      // channel
    const int s = rowstart[n];
    const int e = rowstart[n+1];
    float acc = -INFINITY;
    for (int i = s; i < e; ++i) {
        const int c = rev[i];
        acc = fmaxf(acc, x[(size_t)c * CIN + lane]);
    }
    if (e == s) acc = 0.f;                                  // empty row -> 0 (torch_scatter)
    pooled[(size_t)n * CIN + lane] = acc;
}

// ---------------- K4: y = pooled @ W^T + b ----------------
__global__ __launch_bounds__(256,2) void k4_linear(const float* __restrict__ pooled, const float* __restrict__ W,
                                                   const float* __restrict__ bias, float* __restrict__ y)
{
    __shared__ float wl[COUT*68];
    __shared__ float pl[64*68];
    const int t  = threadIdx.x;
    const int r0 = blockIdx.x * 64;
    for (int i = 0; i < (COUT*CIN)/256; ++i) {
        int linear = t + 256*i;
        int c = linear >> 6, k = linear & 63;
        wl[c*68 + k] = W[linear];
    }
    for (int i = 0; i < (64*CIN)/256; ++i) {
        int linear = t + 256*i;
        int r = linear >> 6, k = linear & 63;
        pl[r*68 + k] = pooled[(size_t)(r0 + r)*CIN + k];
    }
    __syncthreads();
    const int tx = t & 15;
    const int ty = t >> 4;
    float acc[4][8];
    #pragma unroll
    for (int j = 0; j < 8; ++j) {
        float bj = bias[tx + 16*j];
        #pragma unroll
        for (int i = 0; i < 4; ++i) acc[i][j] = bj;
    }
    for (int k = 0; k < CIN; k += 4) {
        float4 a[4], bb[8];
        #pragma unroll
        for (int i = 0; i < 4; ++i) a[i]  = *reinterpret_cast<const float4*>(&pl[(ty*4+i)*68 + k]);
        #pragma unroll
        for (int j = 0; j < 8; ++j) bb[j] = *reinterpret_cast<const float4*>(&wl[(tx+16*j)*68 + k]);
        #pragma unroll
        for (int i = 0; i < 4; ++i)
            #pragma unroll
            for (int j = 0; j < 8; ++j) {
                acc[i][j] = fmaf(a[i].x, bb[j].x, acc[i][j]);
                acc[i][j] = fmaf(a[i].y, bb[j].y, acc[i][j]);
                acc[i][j] = fmaf(a[i].z, bb[j].z, acc[i][j]);
                acc[i][j] = fmaf(a[i].w, bb[j].w, acc[i][j]);
            }
    }
    #pragma unroll
    for (int i = 0; i < 4; ++i) {
        float* dst = y + (size_t)(r0 + ty*4 + i) * COUT;
        #pragma unroll
        for (int j = 0; j < 8; ++j) dst[tx + 16*j] = acc[i][j];
    }
}

// ---------------- K5: per-channel sum / sumsq (fp64), 2048 blocks x 32 rows ----------------
__global__ void k5_stats(const float* __restrict__ y, double* __restrict__ sums)
{
    __shared__ double red[512];
    const int t    = threadIdx.x;
    const int ch   = t & 127;
    const int half = t >> 7;
    const size_t base = (size_t)blockIdx.x * 32;
    double s = 0.0, ss = 0.0;
    for (int r = 0; r < 16; ++r) {
        double v = (double)y[(base + (size_t)half*16 + r) * COUT + ch];
        s += v; ss += v*v;
    }
    red[t] = s; red[256 + t] = ss;
    __syncthreads();
    if (half == 0) {
        atomicAdd(&sums[ch],        s  + red[128 + ch]);
        atomicAdd(&sums[COUT + ch], ss + red[256 + 128 + ch]);
    }
}

// ---------------- K6: BN scale/shift ----------------
__global__ void k6_bnparam(const double* __restrict__ sums, const float* __restrict__ gamma,
                           const float* __restrict__ beta, float* __restrict__ scsh)
{
    const int t = threadIdx.x;
    const double mean = sums[t] * (1.0/NTOT);
    const double var  = sums[COUT + t] * (1.0/NTOT) - mean*mean;
    const float inv   = (float)rsqrt(var + 1e-5);
    const float sc    = inv * gamma[t];
    scsh[t]        = sc;
    scsh[COUT + t] = beta[t] - (float)mean * sc;
}

// ---------------- K7: out = relu(y*scale + shift) ----------------
__global__ void k7_bnrelu(const float* __restrict__ y, const float* __restrict__ scsh, float* __restrict__ out)
{
    const int g    = blockIdx.x * blockDim.x + threadIdx.x;
    const int base = g * 4;
    float4 v = *reinterpret_cast<const float4*>(y + base);
    const int ch = base & (COUT-1);
    float4 o;
    o.x = fmaxf(0.f, fmaf(v.x, scsh[ch+0], scsh[COUT+ch+0]));
    o.y = fmaxf(0.f, fmaf(v.y, scsh[ch+1], scsh[COUT+ch+1]));
    o.z = fmaxf(0.f, fmaf(v.z, scsh[ch+2], scsh[COUT+ch+2]));
    o.w = fmaxf(0.f, fmaf(v.w, scsh[ch+3], scsh[COUT+ch+3]));
    *reinterpret_cast<float4*>(out + base) = o;
}

extern "C" void kernel_launch(void* const* d_in, const int* in_sizes, int n_in,
                              void* d_out, int out_size, void* d_ws, size_t ws_size,
                              hipStream_t stream)
{
    const float* x     = (const float*)d_in[0];
    const float* W     = (const float*)d_in[2];
    const float* bias  = (const float*)d_in[3];
    const float* gamma = (const float*)d_in[4];
    const float* beta  = (const float*)d_in[5];
    float* out = (float*)d_out;

    // Workspace (aliasing by liveness; stream order makes each safe):
    //  [0 .. 16.8M)     xhi+xlo (k0/k1)  -> pooled (k3g writes every row, no memset)
    //  [16.8 .. 33.6M)  cand (k1/k2)     -> y[0..16.8M) (k4)
    //  [33.6 .. 37.8M)  nbr (k2/k3a)     -> y[16.8..21M)
    //  [37.8 .. 42.9M)  deg/rowstart/wcur/rev (k2..k3g) -> y tail (k4)
    //  [16.8 .. 50.3M)  y (k4 out; k5/k7 in)
    //  [50.3M ..)       sq, sums, scsh
    char* ws = (char*)d_ws;
    unsigned short* xhi = (unsigned short*)ws;                       // NTOT*64 u16
    unsigned short* xlo = (unsigned short*)(ws + (size_t)NTOT*CIN*2);
    float*  pooled = (float*)ws;                                     // NTOT*64 f32 (aliases xhi/xlo)
    int*    cand   = (int*)(ws + (size_t)NTOT*CIN*4);                // NTOT*64 int
    float*  y      = (float*)(ws + (size_t)NTOT*CIN*4);              // NTOT*128 f32 (aliases cand/nbr/CSR)
    int*    nbr    = (int*)(ws + (size_t)NTOT*(CIN+CIN)*4);          // NTOT*16 int
    char*   csr    = ws + (size_t)NTOT*(CIN+CIN+KNN)*4;              // CSR scratch (dead before k4's writes land)
    int*    deg      = (int*)csr;                                    // NTOT int
    int*    rowstart = (int*)(csr + (size_t)NTOT*4);                 // NTOT+1 int
    int*    wcur     = (int*)(csr + (size_t)(2*NTOT+1)*4);           // NTOT int
    int*    rev      = (int*)(csr + (size_t)(3*NTOT+1)*4);           // NTOT*KNN int
    float*  sq     = (float*)(ws + (size_t)NTOT*(CIN+COUT)*4);       // NTOT f32
    double* sums   = (double*)(ws + (size_t)NTOT*(CIN+COUT+1)*4);    // 2*COUT f64
    float*  scsh   = (float*)((char*)sums + 2*COUT*sizeof(double));

    hipMemsetAsync(deg, 0, (size_t)NTOT*4, stream);
    hipMemsetAsync(sums, 0, 2*COUT*sizeof(double), stream);

    k0_prep  <<<NTOT/256,   256, 0, stream>>>(x, xhi, xlo, sq);
    k1_knn   <<<NTOT/64,    256, 0, stream>>>(xhi, xlo, sq, cand);
    k2_refine<<<NTOT/4,     256, 0, stream>>>(x, cand, nbr, deg);

    k3_scan  <<<1,          256, 0, stream>>>(deg, rowstart, wcur);
    k3_place <<<NTOT*KNN/256,256,0, stream>>>(nbr, wcur, rev);
    k3_gather<<<NTOT/4,     256, 0, stream>>>(x, rowstart, rev, pooled);

    k4_linear <<<NTOT/64, 256, 0, stream>>>(pooled, W, bias, y);
    k5_stats  <<<NTOT/32, 256, 0, stream>>>(y, sums);
    k6_bnparam<<<1,      COUT, 0, stream>>>(sums, gamma, beta, scsh);
    k7_bnrelu <<<(NTOT*COUT/4)/256, 256, 0, stream>>>(y, scsh, out);
}

// Round 8
// 806.358 us; speedup vs baseline: 350.7927x; 1.0217x over previous
//
#include <hip/hip_runtime.h>
#include <hip/hip_bf16.h>
#include <math.h>

#define NPTS 2048
#define NCLOUD 32
#define NTOT (NPTS*NCLOUD)
#define CIN 64
#define COUT 128
#define KNN 16
#define KSUB 16            // per-lane-subset kept candidates (16 = superset guarantee)
#define NCAND 64           // 4 subsets * 16

typedef __attribute__((ext_vector_type(8))) short short8v;   // 8 bf16 (4 VGPR)
typedef __attribute__((ext_vector_type(4))) float float4v;   // 4 fp32

__device__ __forceinline__ unsigned short f2bf(float f) {    // RNE float->bf16
    unsigned u = __float_as_uint(f);
    return (unsigned short)((u + 0x7fffu + ((u >> 16) & 1u)) >> 16);
}
__device__ __forceinline__ float bf2f(unsigned short h) {
    return __uint_as_float(((unsigned)h) << 16);
}

// ---------------- K0: bf16 hi/lo planes + |q|^2 (fp32, ranking-only) ----------------
__global__ void k0_prep(const float* __restrict__ x, unsigned short* __restrict__ xhi,
                        unsigned short* __restrict__ xlo, float* __restrict__ sq)
{
    const int p = blockIdx.x * 256 + threadIdx.x;
    const float* src = x + (size_t)p * CIN;
    float s = 0.f;
    #pragma unroll
    for (int i = 0; i < 8; ++i) {
        float4 v0 = *reinterpret_cast<const float4*>(src + 8*i);
        float4 v1 = *reinterpret_cast<const float4*>(src + 8*i + 4);
        float e[8] = {v0.x,v0.y,v0.z,v0.w,v1.x,v1.y,v1.z,v1.w};
        short8v h, l;
        #pragma unroll
        for (int u = 0; u < 8; ++u) {
            unsigned short hb = f2bf(e[u]);
            h[u] = (short)hb;
            l[u] = (short)f2bf(e[u] - bf2f(hb));
            s = fmaf(e[u], e[u], s);
        }
        *reinterpret_cast<short8v*>(xhi + (size_t)p*CIN + 8*i) = h;
        *reinterpret_cast<short8v*>(xlo + (size_t)p*CIN + 8*i) = l;
    }
    sq[p] = s;
}

// ---------------- K1: MFMA swapped-operand KNN + batched bitonic top-16 ----------------
// Wave owns 16 rows (j=lane&15); quad (lane>>4) covers column subset {quad*4+r + 16*it}.
// Selection: per outer iter collect 16 packed keys (4 MFMA tiles), bitonic-sort-16 asc,
// half-clean against desc kd[16] (valley-bitonic => low half = exact bottom-16 of union),
// bitonic-merge kd back to desc. Same key set as the bubble version => identical output.
__global__ __launch_bounds__(256,1) void k1_knn(const unsigned short* __restrict__ xhi,
                                                const unsigned short* __restrict__ xlo,
                                                const float* __restrict__ sq,
                                                int* __restrict__ cand)
{
    const int o    = ((blockIdx.x & 7) << 7) + (blockIdx.x >> 3);  // XCD swizzle
    const int wave = threadIdx.x >> 6;
    const int lane = threadIdx.x & 63;
    const int j    = lane & 15;
    const int quad = lane >> 4;
    const int rowglob = o*64 + wave*16 + j;
    const int cbase   = (rowglob >> 11) << 11;     // cloud base point id

    short8v bhi[2], blo[2];
    #pragma unroll
    for (int kk = 0; kk < 2; ++kk) {
        const size_t off = (size_t)rowglob*CIN + quad*8 + kk*32;
        bhi[kk] = *reinterpret_cast<const short8v*>(xhi + off);
        blo[kk] = *reinterpret_cast<const short8v*>(xlo + off);
    }

    unsigned kd[KSUB];                 // sorted DESC: kd[0] = worst kept
    #pragma unroll
    for (int k = 0; k < KSUB; ++k) kd[k] = 0xFFFFFFFFu;

    for (int it4 = 0; it4 < NPTS/64; ++it4) {      // 32 outer iters, 4 tiles each
        unsigned key[16];
        #pragma unroll
        for (int sub = 0; sub < 4; ++sub) {
            const int colb = it4*64 + sub*16;
            const size_t abase = (size_t)(cbase + colb + j)*CIN + quad*8;
            const short8v ahi0 = *reinterpret_cast<const short8v*>(xhi + abase);
            const short8v ahi1 = *reinterpret_cast<const short8v*>(xhi + abase + 32);
            const short8v alo0 = *reinterpret_cast<const short8v*>(xlo + abase);
            const short8v alo1 = *reinterpret_cast<const short8v*>(xlo + abase + 32);

            float4v acc0 = {0.f,0.f,0.f,0.f}, acc1 = {0.f,0.f,0.f,0.f};
            acc0 = __builtin_amdgcn_mfma_f32_16x16x32_bf16(ahi0, bhi[0], acc0, 0,0,0);
            acc0 = __builtin_amdgcn_mfma_f32_16x16x32_bf16(ahi0, blo[0], acc0, 0,0,0);
            acc0 = __builtin_amdgcn_mfma_f32_16x16x32_bf16(alo0, bhi[0], acc0, 0,0,0);
            acc1 = __builtin_amdgcn_mfma_f32_16x16x32_bf16(ahi1, bhi[1], acc1, 0,0,0);
            acc1 = __builtin_amdgcn_mfma_f32_16x16x32_bf16(ahi1, blo[1], acc1, 0,0,0);
            acc1 = __builtin_amdgcn_mfma_f32_16x16x32_bf16(alo1, bhi[1], acc1, 0,0,0);

            const float4v sqv = *reinterpret_cast<const float4v*>(sq + cbase + colb + quad*4);
            const unsigned idxbase = (unsigned)(colb + quad*4);
            #pragma unroll
            for (int r = 0; r < 4; ++r) {
                const float s = fmaf(-2.f, acc0[r] + acc1[r], sqv[r]);
                unsigned u = __float_as_uint(s);
                u ^= (unsigned)(((int)u >> 31) | 0x80000000);   // monotone float->uint
                key[sub*4 + r] = (u & 0xFFFFF800u) | (idxbase + r);
            }
        }

        // bitonic sort key[16] ascending (static indices, full ILP)
        #pragma unroll
        for (int k = 2; k <= 16; k <<= 1) {
            #pragma unroll
            for (int jj = k >> 1; jj > 0; jj >>= 1) {
                #pragma unroll
                for (int i = 0; i < 16; ++i) {
                    const int l = i ^ jj;
                    if (l > i) {
                        const bool asc = ((i & k) == 0);
                        const unsigned a = key[i], b = key[l];
                        const unsigned mn = min(a, b), mx = max(a, b);
                        key[i] = asc ? mn : mx;
                        key[l] = asc ? mx : mn;
                    }
                }
            }
        }
        // half-cleaner: [kd desc | key asc] is valley-bitonic -> low half = bottom-16
        #pragma unroll
        for (int i = 0; i < 16; ++i) kd[i] = min(kd[i], key[i]);
        // kd now bitonic (mountain); bitonic-merge back to desc
        #pragma unroll
        for (int jj = 8; jj > 0; jj >>= 1) {
            #pragma unroll
            for (int i = 0; i < 16; ++i) {
                const int l = i ^ jj;
                if (l > i) {
                    const unsigned a = kd[i], b = kd[l];
                    kd[i] = max(a, b); kd[l] = min(a, b);
                }
            }
        }
    }
    int* dst = cand + (size_t)rowglob*NCAND + quad*KSUB;
    #pragma unroll
    for (int k = 0; k < 4; ++k) {
        int4 w = { (int)(kd[4*k+0] & 0x7FFu), (int)(kd[4*k+1] & 0x7FFu),
                   (int)(kd[4*k+2] & 0x7FFu), (int)(kd[4*k+3] & 0x7FFu) };
        *reinterpret_cast<int4*>(dst + 4*k) = w;
    }
}

// np.sum pairwise-8 replication for 64 squares (fp32, no FMA) — keep BIT-IDENTICAL.
__device__ __forceinline__ float np_sq64(const float* __restrict__ v)
{
    float r[8];
    #pragma unroll
    for (int j = 0; j < 8; ++j) r[j] = __fmul_rn(v[j], v[j]);
    #pragma unroll
    for (int i = 1; i < 8; ++i)
        #pragma unroll
        for (int j = 0; j < 8; ++j) r[j] = __fadd_rn(r[j], __fmul_rn(v[8*i+j], v[8*i+j]));
    return __fadd_rn(__fadd_rn(__fadd_rn(r[0],r[1]), __fadd_rn(r[2],r[3])),
                     __fadd_rn(__fadd_rn(r[4],r[5]), __fadd_rn(r[6],r[7])));
}

// ---------------- K2: wave-per-point exact rerank + in-degree count ----------------
__global__ void k2_refine(const float* __restrict__ x, const int* __restrict__ cand,
                          int* __restrict__ nbr, int* __restrict__ deg)
{
    const int w    = blockIdx.x * 4 + (threadIdx.x >> 6);   // point id
    const int lane = threadIdx.x & 63;
    const int b    = w >> 11;
    const int ploc = w & (NPTS-1);
    const float* xc = x + (size_t)b * NPTS * CIN;
    const float* xp = xc + (size_t)ploc * CIN;

    float xpl[CIN];
    #pragma unroll
    for (int i = 0; i < CIN/4; ++i) {
        float4 v = *reinterpret_cast<const float4*>(xp + 4*i);
        xpl[4*i+0]=v.x; xpl[4*i+1]=v.y; xpl[4*i+2]=v.z; xpl[4*i+3]=v.w;
    }
    const float sqp = np_sq64(xpl);

    const int q = cand[(size_t)w * NCAND + lane];
    const float* xq = xc + (size_t)q * CIN;
    float r[8];
    float dot = 0.f;
    {
        float4 v0 = *reinterpret_cast<const float4*>(xq + 0);
        float4 v1 = *reinterpret_cast<const float4*>(xq + 4);
        float g[8] = {v0.x,v0.y,v0.z,v0.w,v1.x,v1.y,v1.z,v1.w};
        #pragma unroll
        for (int u = 0; u < 8; ++u) {
            r[u] = __fmul_rn(g[u], g[u]);
            dot  = __fadd_rn(dot, __fmul_rn(xpl[u], g[u]));
        }
    }
    #pragma unroll
    for (int i = 1; i < 8; ++i) {
        float4 v0 = *reinterpret_cast<const float4*>(xq + 8*i);
        float4 v1 = *reinterpret_cast<const float4*>(xq + 8*i + 4);
        float g[8] = {v0.x,v0.y,v0.z,v0.w,v1.x,v1.y,v1.z,v1.w};
        #pragma unroll
        for (int u = 0; u < 8; ++u) {
            r[u] = __fadd_rn(r[u], __fmul_rn(g[u], g[u]));
            dot  = __fadd_rn(dot, __fmul_rn(xpl[8*i+u], g[u]));
        }
    }
    const float sqq = __fadd_rn(__fadd_rn(__fadd_rn(r[0],r[1]), __fadd_rn(r[2],r[3])),
                                __fadd_rn(__fadd_rn(r[4],r[5]), __fadd_rn(r[6],r[7])));
    float d = __fsub_rn(__fadd_rn(sqp, sqq), __fmul_rn(2.f, dot));
    if (q == ploc) d = INFINITY;                    // self-exclusion (exact, loop=False)

    int rank = 0;
    for (int s = 0; s < 64; ++s) {                  // exact rank with (d, idx) total order
        float dj = __shfl(d, s);
        int   qj = __shfl(q, s);
        rank += (dj < d || (dj == d && qj < q)) ? 1 : 0;
    }
    if (rank < KNN) {
        const int n = b * NPTS + q;
        nbr[(size_t)w * KNN + rank] = n;
        atomicAdd(&deg[n], 1);                      // in-degree for CSR
    }
}

// ---------------- K3s: exclusive prefix scan of deg (no per-thread arrays!) ----------------
__global__ void k3_scan(const int* __restrict__ deg, int* __restrict__ rowstart, int* __restrict__ wcur)
{
    __shared__ int part[256];
    __shared__ int base[257];
    const int t = threadIdx.x;
    int s = 0;
    for (int i = 0; i < 256; ++i) s += deg[t*256 + i];
    part[t] = s;
    __syncthreads();
    if (t == 0) {
        int acc = 0;
        for (int i = 0; i < 256; ++i) { base[i] = acc; acc += part[i]; }
        base[256] = acc;
    }
    __syncthreads();
    int run = base[t];
    for (int i = 0; i < 256; ++i) {
        rowstart[t*256 + i] = run;
        wcur[t*256 + i] = run;
        run += deg[t*256 + i];
    }
    if (t == 0) rowstart[NTOT] = base[256];
}

// ---------------- K3a: place edges into reverse lists (counter atomics only) ----------------
__global__ void k3_place(const int* __restrict__ nbr, int* __restrict__ wcur, int* __restrict__ rev)
{
    const int e = blockIdx.x * 256 + threadIdx.x;    // edge id
    const int c = e >> 4;                            // center (global point id)
    const int n = nbr[e];                            // neighbor (global point id)
    const int pos = atomicAdd(&wcur[n], 1);
    rev[pos] = c;
}

// ---------------- K3g: gather-max pooled[n] = max over rev(n) of x[c]; empty -> 0 ----------------
__global__ void k3_gather(const float* __restrict__ x, const int* __restrict__ rowstart,
                          const int* __restrict__ rev, float* __restrict__ pooled)
{
    const int n    = blockIdx.x * 4 + (threadIdx.x >> 6);   // point id, one wave each
    const int lane = threadIdx.x & 63;                      // channel
    const int s = rowstart[n];
    const int e = rowstart[n+1];
    float acc = -INFINITY;
    for (int i = s; i < e; ++i) {
        const int c = rev[i];
        acc = fmaxf(acc, x[(size_t)c * CIN + lane]);
    }
    if (e == s) acc = 0.f;                                  // empty row -> 0 (torch_scatter)
    pooled[(size_t)n * CIN + lane] = acc;
}

// ---------------- K4: y = pooled @ W^T + b ----------------
__global__ __launch_bounds__(256,2) void k4_linear(const float* __restrict__ pooled, const float* __restrict__ W,
                                                   const float* __restrict__ bias, float* __restrict__ y)
{
    __shared__ float wl[COUT*68];
    __shared__ float pl[64*68];
    const int t  = threadIdx.x;
    const int r0 = blockIdx.x * 64;
    for (int i = 0; i < (COUT*CIN)/256; ++i) {
        int linear = t + 256*i;
        int c = linear >> 6, k = linear & 63;
        wl[c*68 + k] = W[linear];
    }
    for (int i = 0; i < (64*CIN)/256; ++i) {
        int linear = t + 256*i;
        int r = linear >> 6, k = linear & 63;
        pl[r*68 + k] = pooled[(size_t)(r0 + r)*CIN + k];
    }
    __syncthreads();
    const int tx = t & 15;
    const int ty = t >> 4;
    float acc[4][8];
    #pragma unroll
    for (int j = 0; j < 8; ++j) {
        float bj = bias[tx + 16*j];
        #pragma unroll
        for (int i = 0; i < 4; ++i) acc[i][j] = bj;
    }
    for (int k = 0; k < CIN; k += 4) {
        float4 a[4], bb[8];
        #pragma unroll
        for (int i = 0; i < 4; ++i) a[i]  = *reinterpret_cast<const float4*>(&pl[(ty*4+i)*68 + k]);
        #pragma unroll
        for (int j = 0; j < 8; ++j) bb[j] = *reinterpret_cast<const float4*>(&wl[(tx+16*j)*68 + k]);
        #pragma unroll
        for (int i = 0; i < 4; ++i)
            #pragma unroll
            for (int j = 0; j < 8; ++j) {
                acc[i][j] = fmaf(a[i].x, bb[j].x, acc[i][j]);
                acc[i][j] = fmaf(a[i].y, bb[j].y, acc[i][j]);
                acc[i][j] = fmaf(a[i].z, bb[j].z, acc[i][j]);
                acc[i][j] = fmaf(a[i].w, bb[j].w, acc[i][j]);
            }
    }
    #pragma unroll
    for (int i = 0; i < 4; ++i) {
        float* dst = y + (size_t)(r0 + ty*4 + i) * COUT;
        #pragma unroll
        for (int j = 0; j < 8; ++j) dst[tx + 16*j] = acc[i][j];
    }
}

// ---------------- K5: per-channel sum / sumsq (fp64), 2048 blocks x 32 rows ----------------
__global__ void k5_stats(const float* __restrict__ y, double* __restrict__ sums)
{
    __shared__ double red[512];
    const int t    = threadIdx.x;
    const int ch   = t & 127;
    const int half = t >> 7;
    const size_t base = (size_t)blockIdx.x * 32;
    double s = 0.0, ss = 0.0;
    for (int r = 0; r < 16; ++r) {
        double v = (double)y[(base + (size_t)half*16 + r) * COUT + ch];
        s += v; ss += v*v;
    }
    red[t] = s; red[256 + t] = ss;
    __syncthreads();
    if (half == 0) {
        atomicAdd(&sums[ch],        s  + red[128 + ch]);
        atomicAdd(&sums[COUT + ch], ss + red[256 + 128 + ch]);
    }
}

// ---------------- K6: BN scale/shift ----------------
__global__ void k6_bnparam(const double* __restrict__ sums, const float* __restrict__ gamma,
                           const float* __restrict__ beta, float* __restrict__ scsh)
{
    const int t = threadIdx.x;
    const double mean = sums[t] * (1.0/NTOT);
    const double var  = sums[COUT + t] * (1.0/NTOT) - mean*mean;
    const float inv   = (float)rsqrt(var + 1e-5);
    const float sc    = inv * gamma[t];
    scsh[t]        = sc;
    scsh[COUT + t] = beta[t] - (float)mean * sc;
}

// ---------------- K7: out = relu(y*scale + shift) ----------------
__global__ void k7_bnrelu(const float* __restrict__ y, const float* __restrict__ scsh, float* __restrict__ out)
{
    const int g    = blockIdx.x * blockDim.x + threadIdx.x;
    const int base = g * 4;
    float4 v = *reinterpret_cast<const float4*>(y + base);
    const int ch = base & (COUT-1);
    float4 o;
    o.x = fmaxf(0.f, fmaf(v.x, scsh[ch+0], scsh[COUT+ch+0]));
    o.y = fmaxf(0.f, fmaf(v.y, scsh[ch+1], scsh[COUT+ch+1]));
    o.z = fmaxf(0.f, fmaf(v.z, scsh[ch+2], scsh[COUT+ch+2]));
    o.w = fmaxf(0.f, fmaf(v.w, scsh[ch+3], scsh[COUT+ch+3]));
    *reinterpret_cast<float4*>(out + base) = o;
}

extern "C" void kernel_launch(void* const* d_in, const int* in_sizes, int n_in,
                              void* d_out, int out_size, void* d_ws, size_t ws_size,
                              hipStream_t stream)
{
    const float* x     = (const float*)d_in[0];
    const float* W     = (const float*)d_in[2];
    const float* bias  = (const float*)d_in[3];
    const float* gamma = (const float*)d_in[4];
    const float* beta  = (const float*)d_in[5];
    float* out = (float*)d_out;

    // Workspace (aliasing by liveness; stream order makes each safe)
    char* ws = (char*)d_ws;
    unsigned short* xhi = (unsigned short*)ws;                       // NTOT*64 u16
    unsigned short* xlo = (unsigned short*)(ws + (size_t)NTOT*CIN*2);
    float*  pooled = (float*)ws;                                     // NTOT*64 f32 (aliases xhi/xlo)
    int*    cand   = (int*)(ws + (size_t)NTOT*CIN*4);                // NTOT*64 int
    float*  y      = (float*)(ws + (size_t)NTOT*CIN*4);              // NTOT*128 f32 (aliases cand/nbr/CSR)
    int*    nbr    = (int*)(ws + (size_t)NTOT*(CIN+CIN)*4);          // NTOT*16 int
    char*   csr    = ws + (size_t)NTOT*(CIN+CIN+KNN)*4;              // CSR scratch
    int*    deg      = (int*)csr;                                    // NTOT int
    int*    rowstart = (int*)(csr + (size_t)NTOT*4);                 // NTOT+1 int
    int*    wcur     = (int*)(csr + (size_t)(2*NTOT+1)*4);           // NTOT int
    int*    rev      = (int*)(csr + (size_t)(3*NTOT+1)*4);           // NTOT*KNN int
    float*  sq     = (float*)(ws + (size_t)NTOT*(CIN+COUT)*4);       // NTOT f32
    double* sums   = (double*)(ws + (size_t)NTOT*(CIN+COUT+1)*4);    // 2*COUT f64
    float*  scsh   = (float*)((char*)sums + 2*COUT*sizeof(double));

    hipMemsetAsync(deg, 0, (size_t)NTOT*4, stream);
    hipMemsetAsync(sums, 0, 2*COUT*sizeof(double), stream);

    k0_prep  <<<NTOT/256,   256, 0, stream>>>(x, xhi, xlo, sq);
    k1_knn   <<<NTOT/64,    256, 0, stream>>>(xhi, xlo, sq, cand);
    k2_refine<<<NTOT/4,     256, 0, stream>>>(x, cand, nbr, deg);

    k3_scan  <<<1,          256, 0, stream>>>(deg, rowstart, wcur);
    k3_place <<<NTOT*KNN/256,256,0, stream>>>(nbr, wcur, rev);
    k3_gather<<<NTOT/4,     256, 0, stream>>>(x, rowstart, rev, pooled);

    k4_linear <<<NTOT/64, 256, 0, stream>>>(pooled, W, bias, y);
    k5_stats  <<<NTOT/32, 256, 0, stream>>>(y, sums);
    k6_bnparam<<<1,      COUT, 0, stream>>>(sums, gamma, beta, scsh);
    k7_bnrelu <<<(NTOT*COUT/4)/256, 256, 0, stream>>>(y, scsh, out);
}